// Round 3
// baseline (1252.091 us; speedup 1.0000x reference)
//
#include <hip/hip_runtime.h>
#include <hip/hip_bf16.h>

// Problem dims (fixed)
#define B_SZ 2
#define L_SEQ 512
#define D_MODEL 256
#define D_STATE 128
#define D_CONV 4
#define D_INNER 1024
#define DT_RANK 16
#define N_HEADS 8
#define DK 32
#define D_FF 1024
#define R_TOT (B_SZ * L_SEQ)   // 1024 rows

__device__ inline float silu_f(float x) { return x / (1.f + expf(-x)); }
__device__ inline float softplus_f(float x) { return (x > 20.f) ? x : log1pf(expf(x)); }

// ---------------------------------------------------------------------------
// Generic NT GEMM: C[M,N] = epi( A[M,K] @ W[N,K]^T + bias ) (+ residual)
// all-f32 operands. EPI: 0=none, 1=relu, 2=softplus
// ---------------------------------------------------------------------------
#define GT 64   // tile M and N
#define GK 16   // tile K

template <int EPI>
__global__ __launch_bounds__(256) void gemm_nt(
    const float* __restrict__ A, int lda,
    const float* __restrict__ W, int ldb,
    float* __restrict__ C, int ldc,
    const float* __restrict__ bias,
    const float* __restrict__ res,
    int M, int N, int K)
{
    __shared__ float As[GK][GT + 1];
    __shared__ float Bs[GK][GT + 1];

    const int bm = blockIdx.y * GT;
    const int bn = blockIdx.x * GT;
    const int tid = threadIdx.x;        // 256 threads
    const int tx = tid & 15;            // 0..15
    const int ty = tid >> 4;            // 0..15

    float acc[4][4] = {};

    for (int k0 = 0; k0 < K; k0 += GK) {
        const int r = tid >> 2;          // 0..63
        const int kk = (tid & 3) * 4;    // 0,4,8,12
        const int gm = bm + r;
        const int gn = bn + r;
#pragma unroll
        for (int q = 0; q < 4; ++q) {
            const int gk = k0 + kk + q;
            As[kk + q][r] = (gm < M && gk < K) ? A[(long)gm * lda + gk] : 0.f;
            Bs[kk + q][r] = (gn < N && gk < K) ? W[(long)gn * ldb + gk] : 0.f;
        }
        __syncthreads();
#pragma unroll
        for (int k = 0; k < GK; ++k) {
            float a[4], b[4];
#pragma unroll
            for (int i = 0; i < 4; ++i) a[i] = As[k][ty * 4 + i];
#pragma unroll
            for (int j = 0; j < 4; ++j) b[j] = Bs[k][tx * 4 + j];
#pragma unroll
            for (int i = 0; i < 4; ++i)
#pragma unroll
                for (int j = 0; j < 4; ++j)
                    acc[i][j] = fmaf(a[i], b[j], acc[i][j]);
        }
        __syncthreads();
    }

#pragma unroll
    for (int i = 0; i < 4; ++i) {
        const int gm = bm + ty * 4 + i;
        if (gm >= M) continue;
#pragma unroll
        for (int j = 0; j < 4; ++j) {
            const int gn = bn + tx * 4 + j;
            if (gn >= N) continue;
            float v = acc[i][j];
            if (bias) v += bias[gn];
            if (EPI == 1) v = fmaxf(v, 0.f);
            if (EPI == 2) v = softplus_f(v);
            const long ci = (long)gm * ldc + gn;
            if (res) v += res[ci];
            C[ci] = v;
        }
    }
}

// ---------------------------------------------------------------------------
// LayerNorm (reference semantics: sample var /(d-1), denom = std + eps)
// one block (256 threads) per row, D_MODEL=256
// ---------------------------------------------------------------------------
__global__ __launch_bounds__(256) void ln_kernel(
    const float* __restrict__ x, const float* __restrict__ a,
    const float* __restrict__ bvec, float* __restrict__ out)
{
    const int row = blockIdx.x;
    const int t = threadIdx.x;
    const float v = x[(long)row * D_MODEL + t];
    __shared__ float r1[256], r2[256];
    r1[t] = v;
    r2[t] = v * v;
    __syncthreads();
    for (int s = 128; s > 0; s >>= 1) {
        if (t < s) { r1[t] += r1[t + s]; r2[t] += r2[t + s]; }
        __syncthreads();
    }
    const float mean = r1[0] * (1.f / 256.f);
    const float var = (r2[0] - 256.f * mean * mean) * (1.f / 255.f);
    const float sd = sqrtf(fmaxf(var, 0.f));
    const float o = a[t] * (v - mean) / (sd + 1e-6f) + bvec[t];
    out[(long)row * D_MODEL + t] = o;
}

// ---------------------------------------------------------------------------
// Causal depthwise conv (k=4) + SiLU:  xz[:, :D_INNER] -> u
// ---------------------------------------------------------------------------
__global__ __launch_bounds__(256) void conv_silu_kernel(
    const float* __restrict__ xz, const float* __restrict__ cw,
    const float* __restrict__ cb, float* __restrict__ u)
{
    const long i = (long)blockIdx.x * 256 + threadIdx.x;
    if (i >= (long)R_TOT * D_INNER) return;
    const int d = (int)(i % D_INNER);
    const long row = i / D_INNER;
    const int l = (int)(row % L_SEQ);
    const long b = row / L_SEQ;
    float s = cb[d];
#pragma unroll
    for (int k = 0; k < D_CONV; ++k) {
        const int ls = l - (D_CONV - 1) + k;
        if (ls >= 0)
            s += xz[((b * L_SEQ + ls) * (2 * D_INNER)) + d] * cw[d * D_CONV + k];
    }
    u[i] = silu_f(s);
}

// ---------------------------------------------------------------------------
// Selective scan. grid = B * (D_INNER/4), block = 64 (one wave).
// tid = dl*16 + ng ; lane owns 8 states n = ng*8..ng*8+7 of channel d.
// ---------------------------------------------------------------------------
__global__ __launch_bounds__(64) void scan_kernel(
    const float* __restrict__ dt, const float* __restrict__ u,
    const float* __restrict__ dbl, const float* __restrict__ A_log,
    float* __restrict__ ys)
{
    const int blk = blockIdx.x;
    const int b = blk / (D_INNER / 4);
    const int dch = blk % (D_INNER / 4);
    const int tid = threadIdx.x;
    const int dl = tid >> 4;
    const int ng = tid & 15;
    const int d = dch * 4 + dl;
    const int n0 = ng * 8;

    float An[8], h[8];
#pragma unroll
    for (int j = 0; j < 8; ++j) {
        An[j] = -expf(A_log[(long)d * D_STATE + n0 + j]);
        h[j] = 0.f;
    }
    const long base = (long)b * L_SEQ;
    for (int l = 0; l < L_SEQ; ++l) {
        const long row = base + l;
        const float dtv = dt[row * D_INNER + d];
        const float uv = u[row * D_INNER + d];
        const float* bl = dbl + row * (DT_RANK + 2 * D_STATE);
        const float dtu = dtv * uv;
        float yp = 0.f;
#pragma unroll
        for (int j = 0; j < 8; ++j) {
            const float dA = expf(dtv * An[j]);
            h[j] = fmaf(dA, h[j], dtu * bl[DT_RANK + n0 + j]);
            yp = fmaf(h[j], bl[DT_RANK + D_STATE + n0 + j], yp);
        }
#pragma unroll
        for (int off = 8; off > 0; off >>= 1) yp += __shfl_down(yp, off, 16);
        if (ng == 0) ys[row * D_INNER + d] = yp;
    }
}

// ---------------------------------------------------------------------------
// y = (ys + u*Dp) * silu(z)
// ---------------------------------------------------------------------------
__global__ __launch_bounds__(256) void gate_kernel(
    const float* __restrict__ ys, const float* __restrict__ u,
    const float* __restrict__ Dp, const float* __restrict__ xz,
    float* __restrict__ y)
{
    const long i = (long)blockIdx.x * 256 + threadIdx.x;
    if (i >= (long)R_TOT * D_INNER) return;
    const int d = (int)(i % D_INNER);
    const long row = i / D_INNER;
    const float z = xz[row * (2 * D_INNER) + D_INNER + d];
    y[i] = (ys[i] + u[i] * Dp[d]) * silu_f(z);
}

// ---------------------------------------------------------------------------
// Cross-attention (mask all-true). grid = B*H*L blocks, block = 256.
// ---------------------------------------------------------------------------
__global__ __launch_bounds__(256) void attn_kernel(
    const float* __restrict__ q, const float* __restrict__ k,
    const float* __restrict__ v, float* __restrict__ o)
{
    const int bid = blockIdx.x;
    const int qi = bid % L_SEQ;
    const int hh = (bid / L_SEQ) % N_HEADS;
    const int b = bid / (L_SEQ * N_HEADS);
    const int t = threadIdx.x;

    __shared__ float sc[L_SEQ];
    __shared__ float red[256];
    __shared__ float qv[DK];

    const float scale = 0.17677669529663687f;  // 1/sqrt(32)
    const long qbase = ((long)(b * L_SEQ + qi) * D_MODEL + hh * DK);
    if (t < DK) qv[t] = q[qbase + t];
    __syncthreads();

    for (int j = t; j < L_SEQ; j += 256) {
        const float* krow = k + ((long)(b * L_SEQ + j) * D_MODEL + hh * DK);
        float s = 0.f;
#pragma unroll
        for (int d2 = 0; d2 < DK; ++d2) s = fmaf(qv[d2], krow[d2], s);
        sc[j] = s * scale;
    }
    __syncthreads();

    float m = -INFINITY;
    for (int j = t; j < L_SEQ; j += 256) m = fmaxf(m, sc[j]);
    red[t] = m;
    __syncthreads();
    for (int s = 128; s > 0; s >>= 1) {
        if (t < s) red[t] = fmaxf(red[t], red[t + s]);
        __syncthreads();
    }
    m = red[0];
    __syncthreads();

    float sum = 0.f;
    for (int j = t; j < L_SEQ; j += 256) {
        const float e = expf(sc[j] - m);
        sc[j] = e;
        sum += e;
    }
    red[t] = sum;
    __syncthreads();
    for (int s = 128; s > 0; s >>= 1) {
        if (t < s) red[t] += red[t + s];
        __syncthreads();
    }
    const float inv = 1.f / red[0];
    __syncthreads();

    const int d = t & 31;
    const int g = t >> 5;
    float acc = 0.f;
    for (int j = g; j < L_SEQ; j += 8)
        acc = fmaf(sc[j], v[(long)(b * L_SEQ + j) * D_MODEL + hh * DK + d], acc);
    red[t] = acc;
    __syncthreads();
    if (t < DK) {
        float s2 = 0.f;
#pragma unroll
        for (int gg = 0; gg < 8; ++gg) s2 += red[gg * 32 + t];
        o[qbase + t] = s2 * inv;
    }
}

// ---------------------------------------------------------------------------

extern "C" void kernel_launch(void* const* d_in, const int* in_sizes, int n_in,
                              void* d_out, int out_size, void* d_ws, size_t ws_size,
                              hipStream_t stream) {
    // All tensors are float32 (reference is all-f32 JAX).
    const float* X   = (const float*)d_in[0];
    const float* MEM = (const float*)d_in[1];
    // d_in[2]/d_in[3]: boolean masks, all-true -> unused
    const float* INW = (const float*)d_in[4];
    const float* CW  = (const float*)d_in[5];
    const float* CB  = (const float*)d_in[6];
    const float* XPW = (const float*)d_in[7];
    const float* DTW = (const float*)d_in[8];
    const float* DTB = (const float*)d_in[9];
    const float* ALG = (const float*)d_in[10];
    const float* DP  = (const float*)d_in[11];
    const float* OPW = (const float*)d_in[12];
    const float* N1A = (const float*)d_in[13];
    const float* N1B = (const float*)d_in[14];
    const float* N2A = (const float*)d_in[15];
    const float* N2B = (const float*)d_in[16];
    const float* N3A = (const float*)d_in[17];
    const float* N3B = (const float*)d_in[18];
    const float* WQ  = (const float*)d_in[19];
    const float* WQB = (const float*)d_in[20];
    const float* WK  = (const float*)d_in[21];
    const float* WKB = (const float*)d_in[22];
    const float* WV  = (const float*)d_in[23];
    const float* WVB = (const float*)d_in[24];
    const float* WO  = (const float*)d_in[25];
    const float* WOB = (const float*)d_in[26];
    const float* W1  = (const float*)d_in[27];
    const float* W1B = (const float*)d_in[28];
    const float* W2  = (const float*)d_in[29];
    const float* W2B = (const float*)d_in[30];
    float* out = (float*)d_out;

    // ---- activation workspace (f32) ----
    float* p = (float*)d_ws;
    float* ln1 = p;                                  p += (long)R_TOT * D_MODEL;
    float* xz  = p;                                  p += (long)R_TOT * 2 * D_INNER;
    float* u   = p;                                  p += (long)R_TOT * D_INNER;
    float* dbl = p;                                  p += (long)R_TOT * (DT_RANK + 2 * D_STATE);
    float* dtb = p;                                  p += (long)R_TOT * D_INNER;
    float* ysb = p;                                  p += (long)R_TOT * D_INNER;
    float* yb  = p;                                  p += (long)R_TOT * D_INNER;
    float* h1  = p;                                  p += (long)R_TOT * D_MODEL;
    float* ln2 = p;                                  p += (long)R_TOT * D_MODEL;
    float* qb  = p;                                  p += (long)R_TOT * D_MODEL;
    float* kb  = p;                                  p += (long)R_TOT * D_MODEL;
    float* vb  = p;                                  p += (long)R_TOT * D_MODEL;
    float* ao  = p;                                  p += (long)R_TOT * D_MODEL;
    float* h2  = p;                                  p += (long)R_TOT * D_MODEL;
    float* ln3 = p;                                  p += (long)R_TOT * D_MODEL;
    float* ffa = p;                                  p += (long)R_TOT * D_FF;

    const dim3 blk256(256);
    const long NE = (long)R_TOT * D_INNER;
    const int ew_grid = (int)((NE + 255) / 256);

    // 1. ln1 = LN(x)
    ln_kernel<<<R_TOT, blk256, 0, stream>>>(X, N1A, N1B, ln1);

    // 2. xz = ln1 @ in_proj_w^T   [R,2048]
    gemm_nt<0><<<dim3(2 * D_INNER / GT, R_TOT / GT), blk256, 0, stream>>>(
        ln1, D_MODEL, INW, D_MODEL, xz, 2 * D_INNER, nullptr, nullptr,
        R_TOT, 2 * D_INNER, D_MODEL);

    // 3. u = silu(conv(xi) + conv_b)
    conv_silu_kernel<<<ew_grid, blk256, 0, stream>>>(xz, CW, CB, u);

    // 4. dbl = u @ x_proj_w^T   [R,272]
    gemm_nt<0><<<dim3((DT_RANK + 2 * D_STATE + GT - 1) / GT, R_TOT / GT), blk256, 0, stream>>>(
        u, D_INNER, XPW, D_INNER, dbl, DT_RANK + 2 * D_STATE, nullptr, nullptr,
        R_TOT, DT_RANK + 2 * D_STATE, D_INNER);

    // 5. dt = softplus(dbl[:, :16] @ dt_proj_w^T + dt_proj_b)   [R,1024]
    gemm_nt<2><<<dim3(D_INNER / GT, R_TOT / GT), blk256, 0, stream>>>(
        dbl, DT_RANK + 2 * D_STATE, DTW, DT_RANK, dtb, D_INNER, DTB, nullptr,
        R_TOT, D_INNER, DT_RANK);

    // 6. selective scan -> ys
    scan_kernel<<<B_SZ * (D_INNER / 4), dim3(64), 0, stream>>>(dtb, u, dbl, ALG, ysb);

    // 7. y = (ys + u*Dp) * silu(z)
    gate_kernel<<<ew_grid, blk256, 0, stream>>>(ysb, u, DP, xz, yb);

    // 8. h1 = x + y @ out_proj_w^T
    gemm_nt<0><<<dim3(D_MODEL / GT, R_TOT / GT), blk256, 0, stream>>>(
        yb, D_INNER, OPW, D_INNER, h1, D_MODEL, nullptr, X,
        R_TOT, D_MODEL, D_INNER);

    // 9. ln2 = LN(h1)
    ln_kernel<<<R_TOT, blk256, 0, stream>>>(h1, N2A, N2B, ln2);

    // 10-12. q = ln2@wq^T + b ; k,v = memory@w^T + b
    gemm_nt<0><<<dim3(D_MODEL / GT, R_TOT / GT), blk256, 0, stream>>>(
        ln2, D_MODEL, WQ, D_MODEL, qb, D_MODEL, WQB, nullptr, R_TOT, D_MODEL, D_MODEL);
    gemm_nt<0><<<dim3(D_MODEL / GT, R_TOT / GT), blk256, 0, stream>>>(
        MEM, D_MODEL, WK, D_MODEL, kb, D_MODEL, WKB, nullptr, R_TOT, D_MODEL, D_MODEL);
    gemm_nt<0><<<dim3(D_MODEL / GT, R_TOT / GT), blk256, 0, stream>>>(
        MEM, D_MODEL, WV, D_MODEL, vb, D_MODEL, WVB, nullptr, R_TOT, D_MODEL, D_MODEL);

    // 13. attention -> ao
    attn_kernel<<<B_SZ * N_HEADS * L_SEQ, blk256, 0, stream>>>(qb, kb, vb, ao);

    // 14. h2 = h1 + ao @ wo^T + wo_b
    gemm_nt<0><<<dim3(D_MODEL / GT, R_TOT / GT), blk256, 0, stream>>>(
        ao, D_MODEL, WO, D_MODEL, h2, D_MODEL, WOB, h1, R_TOT, D_MODEL, D_MODEL);

    // 15. ln3 = LN(h2)
    ln_kernel<<<R_TOT, blk256, 0, stream>>>(h2, N3A, N3B, ln3);

    // 16. ffa = relu(ln3 @ w1^T + w1_b)
    gemm_nt<1><<<dim3(D_FF / GT, R_TOT / GT), blk256, 0, stream>>>(
        ln3, D_MODEL, W1, D_MODEL, ffa, D_FF, W1B, nullptr, R_TOT, D_FF, D_MODEL);

    // 17. out = h2 + ffa @ w2^T + w2_b   (f32 out)
    gemm_nt<0><<<dim3(D_MODEL / GT, R_TOT / GT), blk256, 0, stream>>>(
        ffa, D_FF, W2, D_FF, out, D_MODEL, W2B, h2, R_TOT, D_MODEL, D_FF);

    (void)in_sizes; (void)n_in; (void)out_size; (void)ws_size;
}

// Round 4
// 1242.749 us; speedup vs baseline: 1.0075x; 1.0075x over previous
//
#include <hip/hip_runtime.h>
#include <hip/hip_bf16.h>

// Problem dims (fixed)
#define B_SZ 2
#define L_SEQ 512
#define D_MODEL 256
#define D_STATE 128
#define D_CONV 4
#define D_INNER 1024
#define DT_RANK 16
#define N_HEADS 8
#define DK 32
#define D_FF 1024
#define R_TOT (B_SZ * L_SEQ)   // 1024 rows
#define DBL_LD (DT_RANK + 2 * D_STATE)  // 272

__device__ inline float silu_f(float x) { return x / (1.f + expf(-x)); }
__device__ inline float softplus_f(float x) { return (x > 20.f) ? x : log1pf(expf(x)); }

// ---------------------------------------------------------------------------
// GEMM: C[M,N] = epi( A[M,K] @ W[N,K]^T + bias ) (+ residual)
// 128x128 tile, 256 threads, 8x8 micro-tile, float4 global + LDS reads.
// K must be a multiple of 16 and rows 16B-aligned (lda/ldb % 4 == 0). EPI:
// 0=none, 1=relu, 2=softplus
// ---------------------------------------------------------------------------
#define TM 128
#define TK 16

template <int EPI>
__global__ __launch_bounds__(256) void gemm128(
    const float* __restrict__ A, int lda,
    const float* __restrict__ W, int ldb,
    float* __restrict__ C, int ldc,
    const float* __restrict__ bias,
    const float* __restrict__ res,
    int M, int N, int K)
{
    __shared__ float As[TK][TM];
    __shared__ float Bs[TK][TM];

    const int bm = blockIdx.y * TM;
    const int bn = blockIdx.x * TM;
    const int tid = threadIdx.x;
    const int tx = tid & 15;         // n-group 0..15
    const int ty = tid >> 4;         // m-group 0..15
    const int r  = tid >> 1;         // staging row 0..127
    const int kq = (tid & 1) * 8;    // staging k-offset 0 or 8

    float acc[8][8] = {};

    for (int k0 = 0; k0 < K; k0 += TK) {
        // ---- stage A tile (128 rows x 16 k) ----
        {
            const int gm = bm + r;
            float4 v0 = {0.f,0.f,0.f,0.f}, v1 = {0.f,0.f,0.f,0.f};
            if (gm < M) {
                const float* ap = &A[(long)gm * lda + k0 + kq];
                v0 = *(const float4*)ap;
                v1 = *(const float4*)(ap + 4);
            }
            As[kq + 0][r] = v0.x; As[kq + 1][r] = v0.y;
            As[kq + 2][r] = v0.z; As[kq + 3][r] = v0.w;
            As[kq + 4][r] = v1.x; As[kq + 5][r] = v1.y;
            As[kq + 6][r] = v1.z; As[kq + 7][r] = v1.w;

            const int gn = bn + r;
            float4 w0 = {0.f,0.f,0.f,0.f}, w1 = {0.f,0.f,0.f,0.f};
            if (gn < N) {
                const float* wp = &W[(long)gn * ldb + k0 + kq];
                w0 = *(const float4*)wp;
                w1 = *(const float4*)(wp + 4);
            }
            Bs[kq + 0][r] = w0.x; Bs[kq + 1][r] = w0.y;
            Bs[kq + 2][r] = w0.z; Bs[kq + 3][r] = w0.w;
            Bs[kq + 4][r] = w1.x; Bs[kq + 5][r] = w1.y;
            Bs[kq + 6][r] = w1.z; Bs[kq + 7][r] = w1.w;
        }
        __syncthreads();

#pragma unroll
        for (int k = 0; k < TK; ++k) {
            const float4 a0 = *(const float4*)&As[k][ty * 4];
            const float4 a1 = *(const float4*)&As[k][ty * 4 + 64];
            const float4 b0 = *(const float4*)&Bs[k][tx * 4];
            const float4 b1 = *(const float4*)&Bs[k][tx * 4 + 64];
            const float av[8] = {a0.x,a0.y,a0.z,a0.w,a1.x,a1.y,a1.z,a1.w};
            const float bv[8] = {b0.x,b0.y,b0.z,b0.w,b1.x,b1.y,b1.z,b1.w};
#pragma unroll
            for (int i = 0; i < 8; ++i)
#pragma unroll
                for (int j = 0; j < 8; ++j)
                    acc[i][j] = fmaf(av[i], bv[j], acc[i][j]);
        }
        __syncthreads();
    }

    // ---- epilogue ----
#pragma unroll
    for (int i = 0; i < 8; ++i) {
        const int gm = bm + ((i < 4) ? (ty * 4 + i) : (64 + ty * 4 + i - 4));
        if (gm >= M) continue;
#pragma unroll
        for (int j = 0; j < 8; ++j) {
            const int gn = bn + ((j < 4) ? (tx * 4 + j) : (64 + tx * 4 + j - 4));
            if (gn >= N) continue;
            float vv = acc[i][j];
            if (bias) vv += bias[gn];
            if (EPI == 1) vv = fmaxf(vv, 0.f);
            if (EPI == 2) vv = softplus_f(vv);
            const long ci = (long)gm * ldc + gn;
            if (res) vv += res[ci];
            C[ci] = vv;
        }
    }
}

// ---------------------------------------------------------------------------
// LayerNorm (reference semantics: sample var /(d-1), denom = std + eps)
// ---------------------------------------------------------------------------
__global__ __launch_bounds__(256) void ln_kernel(
    const float* __restrict__ x, const float* __restrict__ a,
    const float* __restrict__ bvec, float* __restrict__ out)
{
    const int row = blockIdx.x;
    const int t = threadIdx.x;
    const float v = x[(long)row * D_MODEL + t];
    __shared__ float r1[256], r2[256];
    r1[t] = v;
    r2[t] = v * v;
    __syncthreads();
    for (int s = 128; s > 0; s >>= 1) {
        if (t < s) { r1[t] += r1[t + s]; r2[t] += r2[t + s]; }
        __syncthreads();
    }
    const float mean = r1[0] * (1.f / 256.f);
    const float var = (r2[0] - 256.f * mean * mean) * (1.f / 255.f);
    const float sd = sqrtf(fmaxf(var, 0.f));
    const float o = a[t] * (v - mean) / (sd + 1e-6f) + bvec[t];
    out[(long)row * D_MODEL + t] = o;
}

// ---------------------------------------------------------------------------
// Causal depthwise conv (k=4) + SiLU:  xz[:, :D_INNER] -> u
// ---------------------------------------------------------------------------
__global__ __launch_bounds__(256) void conv_silu_kernel(
    const float* __restrict__ xz, const float* __restrict__ cw,
    const float* __restrict__ cb, float* __restrict__ u)
{
    const long i = (long)blockIdx.x * 256 + threadIdx.x;
    if (i >= (long)R_TOT * D_INNER) return;
    const int d = (int)(i % D_INNER);
    const long row = i / D_INNER;
    const int l = (int)(row % L_SEQ);
    const long b = row / L_SEQ;
    float s = cb[d];
#pragma unroll
    for (int k = 0; k < D_CONV; ++k) {
        const int ls = l - (D_CONV - 1) + k;
        if (ls >= 0)
            s += xz[((b * L_SEQ + ls) * (2 * D_INNER)) + d] * cw[d * D_CONV + k];
    }
    u[i] = silu_f(s);
}

// ---------------------------------------------------------------------------
// Selective scan with register software-pipelining (prefetch step l+1 while
// computing step l). grid = B*(D_INNER/4) blocks x 64 threads (one wave).
// tid = dl*16 + ng ; lane owns 8 states n = ng*8..+7 of channel d.
// ---------------------------------------------------------------------------
__global__ __launch_bounds__(64) void scan_kernel(
    const float* __restrict__ dt, const float* __restrict__ u,
    const float* __restrict__ dbl, const float* __restrict__ A_log,
    float* __restrict__ ys)
{
    const int blk = blockIdx.x;
    const int b = blk / (D_INNER / 4);
    const int dch = blk % (D_INNER / 4);
    const int tid = threadIdx.x;
    const int dl = tid >> 4;
    const int ng = tid & 15;
    const int d = dch * 4 + dl;
    const int n0 = ng * 8;

    float An[8], h[8];
#pragma unroll
    for (int j = 0; j < 8; ++j) {
        An[j] = -expf(A_log[(long)d * D_STATE + n0 + j]);
        h[j] = 0.f;
    }
    const long base = (long)b * L_SEQ;
    const float* dt_p = dt + base * D_INNER + d;
    const float* u_p  = u  + base * D_INNER + d;
    const float* bl_p = dbl + base * DBL_LD + DT_RANK + n0;            // B slice
    const float* cl_p = dbl + base * DBL_LD + DT_RANK + D_STATE + n0;  // C slice

    // prologue loads (l = 0)
    float dtv = dt_p[0];
    float uv  = u_p[0];
    float4 Bv0 = *(const float4*)&bl_p[0];
    float4 Bv1 = *(const float4*)&bl_p[4];
    float4 Cv0 = *(const float4*)&cl_p[0];
    float4 Cv1 = *(const float4*)&cl_p[4];

    for (int l = 0; l < L_SEQ; ++l) {
        // prefetch l+1 (issued before the exp-heavy compute; consumed after)
        float dtn = 0.f, un = 0.f;
        float4 Bn0 = {0,0,0,0}, Bn1 = {0,0,0,0}, Cn0 = {0,0,0,0}, Cn1 = {0,0,0,0};
        if (l + 1 < L_SEQ) {
            dtn = dt_p[(long)(l + 1) * D_INNER];
            un  = u_p[(long)(l + 1) * D_INNER];
            Bn0 = *(const float4*)&bl_p[(long)(l + 1) * DBL_LD];
            Bn1 = *(const float4*)&bl_p[(long)(l + 1) * DBL_LD + 4];
            Cn0 = *(const float4*)&cl_p[(long)(l + 1) * DBL_LD];
            Cn1 = *(const float4*)&cl_p[(long)(l + 1) * DBL_LD + 4];
        }

        const float dtu = dtv * uv;
        const float Bf[8] = {Bv0.x,Bv0.y,Bv0.z,Bv0.w,Bv1.x,Bv1.y,Bv1.z,Bv1.w};
        const float Cf[8] = {Cv0.x,Cv0.y,Cv0.z,Cv0.w,Cv1.x,Cv1.y,Cv1.z,Cv1.w};
        float yp = 0.f;
#pragma unroll
        for (int j = 0; j < 8; ++j) {
            const float dA = expf(dtv * An[j]);
            h[j] = fmaf(dA, h[j], dtu * Bf[j]);
            yp = fmaf(h[j], Cf[j], yp);
        }
#pragma unroll
        for (int off = 8; off > 0; off >>= 1) yp += __shfl_down(yp, off, 16);
        if (ng == 0) ys[(base + l) * D_INNER + d] = yp;

        dtv = dtn; uv = un; Bv0 = Bn0; Bv1 = Bn1; Cv0 = Cn0; Cv1 = Cn1;
    }
}

// ---------------------------------------------------------------------------
// y = (ys + u*Dp) * silu(z)
// ---------------------------------------------------------------------------
__global__ __launch_bounds__(256) void gate_kernel(
    const float* __restrict__ ys, const float* __restrict__ u,
    const float* __restrict__ Dp, const float* __restrict__ xz,
    float* __restrict__ y)
{
    const long i = (long)blockIdx.x * 256 + threadIdx.x;
    if (i >= (long)R_TOT * D_INNER) return;
    const int d = (int)(i % D_INNER);
    const long row = i / D_INNER;
    const float z = xz[row * (2 * D_INNER) + D_INNER + d];
    y[i] = (ys[i] + u[i] * Dp[d]) * silu_f(z);
}

// ---------------------------------------------------------------------------
// Flash-style cross-attention (mask all-true).
// grid = (L/64, H, B), 256 threads. Thread t: lane=t&7 (k-split),
// qa=t>>3 (0..31) -> owns q rows qt*64+qa and +32. K/V chunks staged in LDS.
// ---------------------------------------------------------------------------
#define QT 64
#define CK 64   // k-chunk

__global__ __launch_bounds__(256) void attn_kernel(
    const float* __restrict__ q, const float* __restrict__ k,
    const float* __restrict__ v, float* __restrict__ o)
{
    const int qt = blockIdx.x;
    const int hh = blockIdx.y;
    const int b  = blockIdx.z;
    const int t = threadIdx.x;
    const int lane = t & 7;
    const int qa = t >> 3;
    const int q0 = qt * QT + qa;
    const int q1 = q0 + 32;

    __shared__ float Ks[CK][36];  // +4 pad: 8 consecutive rows cover 32 banks
    __shared__ float Vs[CK][36];

    const float scale = 0.17677669529663687f;  // 1/sqrt(32)
    float qr0[32], qr1[32];
    {
        const float* q0p = q + ((long)(b * L_SEQ + q0) * D_MODEL + hh * DK);
        const float* q1p = q + ((long)(b * L_SEQ + q1) * D_MODEL + hh * DK);
#pragma unroll
        for (int i = 0; i < 8; ++i) {
            const float4 a = *(const float4*)&q0p[i * 4];
            const float4 c = *(const float4*)&q1p[i * 4];
            qr0[i*4+0] = a.x * scale; qr0[i*4+1] = a.y * scale;
            qr0[i*4+2] = a.z * scale; qr0[i*4+3] = a.w * scale;
            qr1[i*4+0] = c.x * scale; qr1[i*4+1] = c.y * scale;
            qr1[i*4+2] = c.z * scale; qr1[i*4+3] = c.w * scale;
        }
    }

    float m0 = -1e30f, l0 = 0.f, o0[32] = {};
    float m1 = -1e30f, l1 = 0.f, o1[32] = {};

    for (int c = 0; c < L_SEQ; c += CK) {
        __syncthreads();   // protect prior-iteration LDS reads
        {
            const int fid = t * 2;               // 0..510, even
            const int row = fid >> 3;            // 0..63
            const int c0  = (fid & 7) * 4;       // 0,8,16,24
            const float* kp = k + ((long)(b * L_SEQ + c + row) * D_MODEL + hh * DK + c0);
            const float* vp = v + ((long)(b * L_SEQ + c + row) * D_MODEL + hh * DK + c0);
            *(float4*)&Ks[row][c0]     = *(const float4*)kp;
            *(float4*)&Ks[row][c0 + 4] = *(const float4*)(kp + 4);
            *(float4*)&Vs[row][c0]     = *(const float4*)vp;
            *(float4*)&Vs[row][c0 + 4] = *(const float4*)(vp + 4);
        }
        __syncthreads();

        // scores for 8 k's per thread
        float s0[8], s1[8];
#pragma unroll
        for (int i = 0; i < 8; ++i) {
            const int kk = i * 8 + lane;
            float a0 = 0.f, a1 = 0.f;
#pragma unroll
            for (int dd = 0; dd < 32; dd += 4) {
                const float4 kv = *(const float4*)&Ks[kk][dd];
                a0 = fmaf(qr0[dd+0], kv.x, a0); a0 = fmaf(qr0[dd+1], kv.y, a0);
                a0 = fmaf(qr0[dd+2], kv.z, a0); a0 = fmaf(qr0[dd+3], kv.w, a0);
                a1 = fmaf(qr1[dd+0], kv.x, a1); a1 = fmaf(qr1[dd+1], kv.y, a1);
                a1 = fmaf(qr1[dd+2], kv.z, a1); a1 = fmaf(qr1[dd+3], kv.w, a1);
            }
            s0[i] = a0; s1[i] = a1;
        }

        // chunk max per q-row (8 local + 8-lane reduce)
        float cm0 = s0[0], cm1 = s1[0];
#pragma unroll
        for (int i = 1; i < 8; ++i) { cm0 = fmaxf(cm0, s0[i]); cm1 = fmaxf(cm1, s1[i]); }
#pragma unroll
        for (int off = 4; off > 0; off >>= 1) {
            cm0 = fmaxf(cm0, __shfl_down(cm0, off, 8));
            cm1 = fmaxf(cm1, __shfl_down(cm1, off, 8));
        }
        cm0 = __shfl(cm0, 0, 8);
        cm1 = __shfl(cm1, 0, 8);

        const float nm0 = fmaxf(m0, cm0);
        const float nm1 = fmaxf(m1, cm1);
        const float al0 = expf(m0 - nm0);   // first chunk: exp(-inf)=0
        const float al1 = expf(m1 - nm1);
        l0 *= al0; l1 *= al1;
#pragma unroll
        for (int dd = 0; dd < 32; ++dd) { o0[dd] *= al0; o1[dd] *= al1; }
        m0 = nm0; m1 = nm1;

        float p0[8], p1[8];
#pragma unroll
        for (int i = 0; i < 8; ++i) {
            p0[i] = expf(s0[i] - m0); l0 += p0[i];
            p1[i] = expf(s1[i] - m1); l1 += p1[i];
        }

        // PV accumulate
#pragma unroll
        for (int i = 0; i < 8; ++i) {
            const int kk = i * 8 + lane;
#pragma unroll
            for (int dd = 0; dd < 32; dd += 4) {
                const float4 vv = *(const float4*)&Vs[kk][dd];
                o0[dd+0] = fmaf(p0[i], vv.x, o0[dd+0]);
                o0[dd+1] = fmaf(p0[i], vv.y, o0[dd+1]);
                o0[dd+2] = fmaf(p0[i], vv.z, o0[dd+2]);
                o0[dd+3] = fmaf(p0[i], vv.w, o0[dd+3]);
                o1[dd+0] = fmaf(p1[i], vv.x, o1[dd+0]);
                o1[dd+1] = fmaf(p1[i], vv.y, o1[dd+1]);
                o1[dd+2] = fmaf(p1[i], vv.z, o1[dd+2]);
                o1[dd+3] = fmaf(p1[i], vv.w, o1[dd+3]);
            }
        }
    }

    // reduce partial sums across the 8 k-split lanes
#pragma unroll
    for (int off = 4; off > 0; off >>= 1) {
        l0 += __shfl_down(l0, off, 8);
        l1 += __shfl_down(l1, off, 8);
#pragma unroll
        for (int dd = 0; dd < 32; ++dd) {
            o0[dd] += __shfl_down(o0[dd], off, 8);
            o1[dd] += __shfl_down(o1[dd], off, 8);
        }
    }
    if (lane == 0) {
        const float i0 = 1.f / l0, i1 = 1.f / l1;
        float* op0 = o + ((long)(b * L_SEQ + q0) * D_MODEL + hh * DK);
        float* op1 = o + ((long)(b * L_SEQ + q1) * D_MODEL + hh * DK);
#pragma unroll
        for (int dd = 0; dd < 32; dd += 4) {
            float4 w0 = {o0[dd]*i0, o0[dd+1]*i0, o0[dd+2]*i0, o0[dd+3]*i0};
            float4 w1 = {o1[dd]*i1, o1[dd+1]*i1, o1[dd+2]*i1, o1[dd+3]*i1};
            *(float4*)&op0[dd] = w0;
            *(float4*)&op1[dd] = w1;
        }
    }
}

// ---------------------------------------------------------------------------

extern "C" void kernel_launch(void* const* d_in, const int* in_sizes, int n_in,
                              void* d_out, int out_size, void* d_ws, size_t ws_size,
                              hipStream_t stream) {
    const float* X   = (const float*)d_in[0];
    const float* MEM = (const float*)d_in[1];
    // d_in[2]/d_in[3]: boolean masks, all-true -> unused
    const float* INW = (const float*)d_in[4];
    const float* CW  = (const float*)d_in[5];
    const float* CB  = (const float*)d_in[6];
    const float* XPW = (const float*)d_in[7];
    const float* DTW = (const float*)d_in[8];
    const float* DTB = (const float*)d_in[9];
    const float* ALG = (const float*)d_in[10];
    const float* DP  = (const float*)d_in[11];
    const float* OPW = (const float*)d_in[12];
    const float* N1A = (const float*)d_in[13];
    const float* N1B = (const float*)d_in[14];
    const float* N2A = (const float*)d_in[15];
    const float* N2B = (const float*)d_in[16];
    const float* N3A = (const float*)d_in[17];
    const float* N3B = (const float*)d_in[18];
    const float* WQ  = (const float*)d_in[19];
    const float* WQB = (const float*)d_in[20];
    const float* WK  = (const float*)d_in[21];
    const float* WKB = (const float*)d_in[22];
    const float* WV  = (const float*)d_in[23];
    const float* WVB = (const float*)d_in[24];
    const float* WO  = (const float*)d_in[25];
    const float* WOB = (const float*)d_in[26];
    const float* W1  = (const float*)d_in[27];
    const float* W1B = (const float*)d_in[28];
    const float* W2  = (const float*)d_in[29];
    const float* W2B = (const float*)d_in[30];
    float* out = (float*)d_out;

    // ---- activation workspace (f32) ----
    float* p = (float*)d_ws;
    float* ln1 = p;                                  p += (long)R_TOT * D_MODEL;
    float* xz  = p;                                  p += (long)R_TOT * 2 * D_INNER;
    float* u   = p;                                  p += (long)R_TOT * D_INNER;
    float* dbl = p;                                  p += (long)R_TOT * DBL_LD;
    float* dtb = p;                                  p += (long)R_TOT * D_INNER;
    float* ysb = p;                                  p += (long)R_TOT * D_INNER;
    float* yb  = p;                                  p += (long)R_TOT * D_INNER;
    float* h1  = p;                                  p += (long)R_TOT * D_MODEL;
    float* ln2 = p;                                  p += (long)R_TOT * D_MODEL;
    float* qb  = p;                                  p += (long)R_TOT * D_MODEL;
    float* kb  = p;                                  p += (long)R_TOT * D_MODEL;
    float* vb  = p;                                  p += (long)R_TOT * D_MODEL;
    float* ao  = p;                                  p += (long)R_TOT * D_MODEL;
    float* h2  = p;                                  p += (long)R_TOT * D_MODEL;
    float* ln3 = p;                                  p += (long)R_TOT * D_MODEL;
    float* ffa = p;                                  p += (long)R_TOT * D_FF;

    const dim3 blk256(256);
    const long NE = (long)R_TOT * D_INNER;
    const int ew_grid = (int)((NE + 255) / 256);
    const int MT = R_TOT / TM;   // 8 m-tiles

    // 1. ln1 = LN(x)
    ln_kernel<<<R_TOT, blk256, 0, stream>>>(X, N1A, N1B, ln1);

    // 2. xz = ln1 @ in_proj_w^T   [R,2048]
    gemm128<0><<<dim3(2 * D_INNER / TM, MT), blk256, 0, stream>>>(
        ln1, D_MODEL, INW, D_MODEL, xz, 2 * D_INNER, nullptr, nullptr,
        R_TOT, 2 * D_INNER, D_MODEL);

    // 3. u = silu(conv(xi) + conv_b)
    conv_silu_kernel<<<ew_grid, blk256, 0, stream>>>(xz, CW, CB, u);

    // 4. dbl = u @ x_proj_w^T   [R,272]
    gemm128<0><<<dim3((DBL_LD + TM - 1) / TM, MT), blk256, 0, stream>>>(
        u, D_INNER, XPW, D_INNER, dbl, DBL_LD, nullptr, nullptr,
        R_TOT, DBL_LD, D_INNER);

    // 5. dt = softplus(dbl[:, :16] @ dt_proj_w^T + dt_proj_b)   [R,1024]
    gemm128<2><<<dim3(D_INNER / TM, MT), blk256, 0, stream>>>(
        dbl, DBL_LD, DTW, DT_RANK, dtb, D_INNER, DTB, nullptr,
        R_TOT, D_INNER, DT_RANK);

    // 6. selective scan -> ys
    scan_kernel<<<B_SZ * (D_INNER / 4), dim3(64), 0, stream>>>(dtb, u, dbl, ALG, ysb);

    // 7. y = (ys + u*Dp) * silu(z)
    gate_kernel<<<ew_grid, blk256, 0, stream>>>(ysb, u, DP, xz, yb);

    // 8. h1 = x + y @ out_proj_w^T
    gemm128<0><<<dim3(D_MODEL / TM, MT), blk256, 0, stream>>>(
        yb, D_INNER, OPW, D_INNER, h1, D_MODEL, nullptr, X,
        R_TOT, D_MODEL, D_INNER);

    // 9. ln2 = LN(h1)
    ln_kernel<<<R_TOT, blk256, 0, stream>>>(h1, N2A, N2B, ln2);

    // 10-12. q = ln2@wq^T + b ; k,v = memory@w^T + b
    gemm128<0><<<dim3(D_MODEL / TM, MT), blk256, 0, stream>>>(
        ln2, D_MODEL, WQ, D_MODEL, qb, D_MODEL, WQB, nullptr, R_TOT, D_MODEL, D_MODEL);
    gemm128<0><<<dim3(D_MODEL / TM, MT), blk256, 0, stream>>>(
        MEM, D_MODEL, WK, D_MODEL, kb, D_MODEL, WKB, nullptr, R_TOT, D_MODEL, D_MODEL);
    gemm128<0><<<dim3(D_MODEL / TM, MT), blk256, 0, stream>>>(
        MEM, D_MODEL, WV, D_MODEL, vb, D_MODEL, WVB, nullptr, R_TOT, D_MODEL, D_MODEL);

    // 13. attention -> ao
    attn_kernel<<<dim3(L_SEQ / QT, N_HEADS, B_SZ), blk256, 0, stream>>>(qb, kb, vb, ao);

    // 14. h2 = h1 + ao @ wo^T + wo_b
    gemm128<0><<<dim3(D_MODEL / TM, MT), blk256, 0, stream>>>(
        ao, D_MODEL, WO, D_MODEL, h2, D_MODEL, WOB, h1, R_TOT, D_MODEL, D_MODEL);

    // 15. ln3 = LN(h2)
    ln_kernel<<<R_TOT, blk256, 0, stream>>>(h2, N3A, N3B, ln3);

    // 16. ffa = relu(ln3 @ w1^T + w1_b)
    gemm128<1><<<dim3(D_FF / TM, MT), blk256, 0, stream>>>(
        ln3, D_MODEL, W1, D_MODEL, ffa, D_FF, W1B, nullptr, R_TOT, D_FF, D_MODEL);

    // 17. out = h2 + ffa @ w2^T + w2_b   (f32 out)
    gemm128<0><<<dim3(D_MODEL / TM, MT), blk256, 0, stream>>>(
        ffa, D_FF, W2, D_FF, out, D_MODEL, W2B, h2, R_TOT, D_MODEL, D_FF);

    (void)in_sizes; (void)n_in; (void)out_size; (void)ws_size;
}

// Round 5
// 1006.000 us; speedup vs baseline: 1.2446x; 1.2353x over previous
//
#include <hip/hip_runtime.h>
#include <hip/hip_bf16.h>

// Problem dims (fixed)
#define B_SZ 2
#define L_SEQ 512
#define D_MODEL 256
#define D_STATE 128
#define D_CONV 4
#define D_INNER 1024
#define DT_RANK 16
#define N_HEADS 8
#define DK 32
#define D_FF 1024
#define R_TOT (B_SZ * L_SEQ)   // 1024 rows
#define DBL_LD (DT_RANK + 2 * D_STATE)  // 272

__device__ inline float silu_f(float x) { return x / (1.f + expf(-x)); }
__device__ inline float softplus_f(float x) { return (x > 20.f) ? x : log1pf(expf(x)); }

// ---------------------------------------------------------------------------
// GEMM: C[M,N] = epi( A[M,K] @ W[N,K]^T + bias ) (+ residual)
// 64x64 tile, 256 threads, 4x4 micro-tile. Shape-aware choice: for M=1024 and
// N in {256..2048} this gives 64..512 workgroups (the 128-tile gave only 16
// for N=256 -> 6% CU utilization, measured regression in round 4).
// EPI: 0=none, 1=relu, 2=softplus
// ---------------------------------------------------------------------------
#define GT 64   // tile M and N
#define GK 16   // tile K

template <int EPI>
__global__ __launch_bounds__(256) void gemm_nt(
    const float* __restrict__ A, int lda,
    const float* __restrict__ W, int ldb,
    float* __restrict__ C, int ldc,
    const float* __restrict__ bias,
    const float* __restrict__ res,
    int M, int N, int K)
{
    __shared__ float As[GK][GT + 1];
    __shared__ float Bs[GK][GT + 1];

    const int bm = blockIdx.y * GT;
    const int bn = blockIdx.x * GT;
    const int tid = threadIdx.x;        // 256 threads
    const int tx = tid & 15;            // 0..15
    const int ty = tid >> 4;            // 0..15

    float acc[4][4] = {};

    for (int k0 = 0; k0 < K; k0 += GK) {
        const int r = tid >> 2;          // 0..63
        const int kk = (tid & 3) * 4;    // 0,4,8,12
        const int gm = bm + r;
        const int gn = bn + r;
#pragma unroll
        for (int q = 0; q < 4; ++q) {
            const int gk = k0 + kk + q;
            As[kk + q][r] = (gm < M && gk < K) ? A[(long)gm * lda + gk] : 0.f;
            Bs[kk + q][r] = (gn < N && gk < K) ? W[(long)gn * ldb + gk] : 0.f;
        }
        __syncthreads();
#pragma unroll
        for (int k = 0; k < GK; ++k) {
            float a[4], b[4];
#pragma unroll
            for (int i = 0; i < 4; ++i) a[i] = As[k][ty * 4 + i];
#pragma unroll
            for (int j = 0; j < 4; ++j) b[j] = Bs[k][tx * 4 + j];
#pragma unroll
            for (int i = 0; i < 4; ++i)
#pragma unroll
                for (int j = 0; j < 4; ++j)
                    acc[i][j] = fmaf(a[i], b[j], acc[i][j]);
        }
        __syncthreads();
    }

#pragma unroll
    for (int i = 0; i < 4; ++i) {
        const int gm = bm + ty * 4 + i;
        if (gm >= M) continue;
#pragma unroll
        for (int j = 0; j < 4; ++j) {
            const int gn = bn + tx * 4 + j;
            if (gn >= N) continue;
            float v = acc[i][j];
            if (bias) v += bias[gn];
            if (EPI == 1) v = fmaxf(v, 0.f);
            if (EPI == 2) v = softplus_f(v);
            const long ci = (long)gm * ldc + gn;
            if (res) v += res[ci];
            C[ci] = v;
        }
    }
}

// ---------------------------------------------------------------------------
// LayerNorm (reference semantics: sample var /(d-1), denom = std + eps)
// ---------------------------------------------------------------------------
__global__ __launch_bounds__(256) void ln_kernel(
    const float* __restrict__ x, const float* __restrict__ a,
    const float* __restrict__ bvec, float* __restrict__ out)
{
    const int row = blockIdx.x;
    const int t = threadIdx.x;
    const float v = x[(long)row * D_MODEL + t];
    __shared__ float r1[256], r2[256];
    r1[t] = v;
    r2[t] = v * v;
    __syncthreads();
    for (int s = 128; s > 0; s >>= 1) {
        if (t < s) { r1[t] += r1[t + s]; r2[t] += r2[t + s]; }
        __syncthreads();
    }
    const float mean = r1[0] * (1.f / 256.f);
    const float var = (r2[0] - 256.f * mean * mean) * (1.f / 255.f);
    const float sd = sqrtf(fmaxf(var, 0.f));
    const float o = a[t] * (v - mean) / (sd + 1e-6f) + bvec[t];
    out[(long)row * D_MODEL + t] = o;
}

// ---------------------------------------------------------------------------
// Causal depthwise conv (k=4) + SiLU:  xz[:, :D_INNER] -> u
// ---------------------------------------------------------------------------
__global__ __launch_bounds__(256) void conv_silu_kernel(
    const float* __restrict__ xz, const float* __restrict__ cw,
    const float* __restrict__ cb, float* __restrict__ u)
{
    const long i = (long)blockIdx.x * 256 + threadIdx.x;
    if (i >= (long)R_TOT * D_INNER) return;
    const int d = (int)(i % D_INNER);
    const long row = i / D_INNER;
    const int l = (int)(row % L_SEQ);
    const long b = row / L_SEQ;
    float s = cb[d];
#pragma unroll
    for (int k = 0; k < D_CONV; ++k) {
        const int ls = l - (D_CONV - 1) + k;
        if (ls >= 0)
            s += xz[((b * L_SEQ + ls) * (2 * D_INNER)) + d] * cw[d * D_CONV + k];
    }
    u[i] = silu_f(s);
}

// ---------------------------------------------------------------------------
// Transpose per batch: in [B*L][1024] row-major -> out[b][d][l] = [B][1024][512]
// 64x64 LDS tiles, coalesced both sides. grid (16, 8, B), 256 threads.
// ---------------------------------------------------------------------------
__global__ __launch_bounds__(256) void trans_kernel(
    const float* __restrict__ in, float* __restrict__ out)
{
    __shared__ float t[64][65];
    const int db = blockIdx.x;   // d-tile 0..15
    const int lb = blockIdx.y;   // l-tile 0..7
    const int b  = blockIdx.z;
    const int tid = threadIdx.x;
    const int r  = tid >> 4;          // 0..15
    const int c4 = (tid & 15) * 4;    // 0..60

#pragma unroll
    for (int q = 0; q < 4; ++q) {
        const int lr = r + q * 16;
        const float4 v = *(const float4*)&in[((long)(b * L_SEQ + lb * 64 + lr)) * D_INNER + db * 64 + c4];
        t[lr][c4 + 0] = v.x; t[lr][c4 + 1] = v.y;
        t[lr][c4 + 2] = v.z; t[lr][c4 + 3] = v.w;
    }
    __syncthreads();
#pragma unroll
    for (int q = 0; q < 4; ++q) {
        const int dr = r + q * 16;
        float4 v;
        v.x = t[c4 + 0][dr]; v.y = t[c4 + 1][dr];
        v.z = t[c4 + 2][dr]; v.w = t[c4 + 3][dr];
        *(float4*)&out[((long)(b * D_INNER + db * 64 + dr)) * L_SEQ + lb * 64 + c4] = v;
    }
}

// ---------------------------------------------------------------------------
// Selective scan v3. One wave per (b,d) channel: 2048 blocks x 64 threads
// (8 waves/CU vs 2 before). Lane owns states n = 2*lane, 2*lane+1.
// Supersteps of 8 with register prefetch of the next superstep.
// dt,u come transposed [b][d][l]; B,C read coalesced from dbl (L2-resident).
// ---------------------------------------------------------------------------
__global__ __launch_bounds__(64) void scan_kernel(
    const float* __restrict__ dtT, const float* __restrict__ uT,
    const float* __restrict__ dbl, const float* __restrict__ A_log,
    float* __restrict__ ys)
{
    const int blk = blockIdx.x;          // 0..2047
    const int b = blk >> 10;
    const int d = blk & 1023;
    const int lane = threadIdx.x;
    const int n0 = lane * 2;

    const float An0 = -expf(A_log[(long)d * D_STATE + n0]);
    const float An1 = -expf(A_log[(long)d * D_STATE + n0 + 1]);
    float h0 = 0.f, h1 = 0.f;

    const float* dtp = dtT + ((long)(b * D_INNER + d) << 9);   // 512 floats
    const float* up  = uT  + ((long)(b * D_INNER + d) << 9);
    const float* blp = dbl + (long)b * L_SEQ * DBL_LD + DT_RANK + n0;      // B
    const float* clp = blp + D_STATE;                                      // C
    float* ysp = ys + ((long)b * L_SEQ) * D_INNER + d;

    // pipeline: current superstep in c*, next prefetched into n*
    float4 dtc0 = *(const float4*)(dtp);
    float4 dtc1 = *(const float4*)(dtp + 4);
    float4 uc0  = *(const float4*)(up);
    float4 uc1  = *(const float4*)(up + 4);
    float2 Bc[8], Cc[8];
#pragma unroll
    for (int j = 0; j < 8; ++j) {
        Bc[j] = *(const float2*)(blp + (long)j * DBL_LD);
        Cc[j] = *(const float2*)(clp + (long)j * DBL_LD);
    }

    for (int s = 0; s < L_SEQ / 8; ++s) {
        const int nb = (s + 1) & (L_SEQ / 8 - 1);   // wraps at end (values unused)
        const float4 dtn0 = *(const float4*)(dtp + nb * 8);
        const float4 dtn1 = *(const float4*)(dtp + nb * 8 + 4);
        const float4 un0  = *(const float4*)(up + nb * 8);
        const float4 un1  = *(const float4*)(up + nb * 8 + 4);
        float2 Bn[8], Cn[8];
#pragma unroll
        for (int j = 0; j < 8; ++j) {
            Bn[j] = *(const float2*)(blp + (long)(nb * 8 + j) * DBL_LD);
            Cn[j] = *(const float2*)(clp + (long)(nb * 8 + j) * DBL_LD);
        }

        const float dts[8] = {dtc0.x, dtc0.y, dtc0.z, dtc0.w, dtc1.x, dtc1.y, dtc1.z, dtc1.w};
        const float us[8]  = {uc0.x,  uc0.y,  uc0.z,  uc0.w,  uc1.x,  uc1.y,  uc1.z,  uc1.w};
#pragma unroll
        for (int j = 0; j < 8; ++j) {
            const float dtv = dts[j];
            const float dtu = dtv * us[j];
            const float dA0 = expf(dtv * An0);
            const float dA1 = expf(dtv * An1);
            h0 = fmaf(dA0, h0, dtu * Bc[j].x);
            h1 = fmaf(dA1, h1, dtu * Bc[j].y);
            float yp = fmaf(h0, Cc[j].x, h1 * Cc[j].y);
#pragma unroll
            for (int off = 32; off > 0; off >>= 1) yp += __shfl_down(yp, off);
            if (lane == 0) ysp[(long)(s * 8 + j) * D_INNER] = yp;
        }

        dtc0 = dtn0; dtc1 = dtn1; uc0 = un0; uc1 = un1;
#pragma unroll
        for (int j = 0; j < 8; ++j) { Bc[j] = Bn[j]; Cc[j] = Cn[j]; }
    }
}

// ---------------------------------------------------------------------------
// y = (ys + u*Dp) * silu(z)
// ---------------------------------------------------------------------------
__global__ __launch_bounds__(256) void gate_kernel(
    const float* __restrict__ ys, const float* __restrict__ u,
    const float* __restrict__ Dp, const float* __restrict__ xz,
    float* __restrict__ y)
{
    const long i = (long)blockIdx.x * 256 + threadIdx.x;
    if (i >= (long)R_TOT * D_INNER) return;
    const int d = (int)(i % D_INNER);
    const long row = i / D_INNER;
    const float z = xz[row * (2 * D_INNER) + D_INNER + d];
    y[i] = (ys[i] + u[i] * Dp[d]) * silu_f(z);
}

// ---------------------------------------------------------------------------
// Flash-style cross-attention (mask all-true).
// grid = (L/64, H, B), 256 threads. lane=t&7 (k-split), qa=t>>3 owns q rows
// qt*64+qa and +32. K/V chunks staged in LDS.
// ---------------------------------------------------------------------------
#define QT 64
#define CK 64   // k-chunk

__global__ __launch_bounds__(256) void attn_kernel(
    const float* __restrict__ q, const float* __restrict__ k,
    const float* __restrict__ v, float* __restrict__ o)
{
    const int qt = blockIdx.x;
    const int hh = blockIdx.y;
    const int b  = blockIdx.z;
    const int t = threadIdx.x;
    const int lane = t & 7;
    const int qa = t >> 3;
    const int q0 = qt * QT + qa;
    const int q1 = q0 + 32;

    __shared__ float Ks[CK][36];
    __shared__ float Vs[CK][36];

    const float scale = 0.17677669529663687f;  // 1/sqrt(32)
    float qr0[32], qr1[32];
    {
        const float* q0p = q + ((long)(b * L_SEQ + q0) * D_MODEL + hh * DK);
        const float* q1p = q + ((long)(b * L_SEQ + q1) * D_MODEL + hh * DK);
#pragma unroll
        for (int i = 0; i < 8; ++i) {
            const float4 a = *(const float4*)&q0p[i * 4];
            const float4 c = *(const float4*)&q1p[i * 4];
            qr0[i*4+0] = a.x * scale; qr0[i*4+1] = a.y * scale;
            qr0[i*4+2] = a.z * scale; qr0[i*4+3] = a.w * scale;
            qr1[i*4+0] = c.x * scale; qr1[i*4+1] = c.y * scale;
            qr1[i*4+2] = c.z * scale; qr1[i*4+3] = c.w * scale;
        }
    }

    float m0 = -1e30f, l0 = 0.f, o0[32] = {};
    float m1 = -1e30f, l1 = 0.f, o1[32] = {};

    for (int c = 0; c < L_SEQ; c += CK) {
        __syncthreads();
        {
            const int fid = t * 2;
            const int row = fid >> 3;
            const int c0  = (fid & 7) * 4;
            const float* kp = k + ((long)(b * L_SEQ + c + row) * D_MODEL + hh * DK + c0);
            const float* vp = v + ((long)(b * L_SEQ + c + row) * D_MODEL + hh * DK + c0);
            *(float4*)&Ks[row][c0]     = *(const float4*)kp;
            *(float4*)&Ks[row][c0 + 4] = *(const float4*)(kp + 4);
            *(float4*)&Vs[row][c0]     = *(const float4*)vp;
            *(float4*)&Vs[row][c0 + 4] = *(const float4*)(vp + 4);
        }
        __syncthreads();

        float s0[8], s1[8];
#pragma unroll
        for (int i = 0; i < 8; ++i) {
            const int kk = i * 8 + lane;
            float a0 = 0.f, a1 = 0.f;
#pragma unroll
            for (int dd = 0; dd < 32; dd += 4) {
                const float4 kv = *(const float4*)&Ks[kk][dd];
                a0 = fmaf(qr0[dd+0], kv.x, a0); a0 = fmaf(qr0[dd+1], kv.y, a0);
                a0 = fmaf(qr0[dd+2], kv.z, a0); a0 = fmaf(qr0[dd+3], kv.w, a0);
                a1 = fmaf(qr1[dd+0], kv.x, a1); a1 = fmaf(qr1[dd+1], kv.y, a1);
                a1 = fmaf(qr1[dd+2], kv.z, a1); a1 = fmaf(qr1[dd+3], kv.w, a1);
            }
            s0[i] = a0; s1[i] = a1;
        }

        float cm0 = s0[0], cm1 = s1[0];
#pragma unroll
        for (int i = 1; i < 8; ++i) { cm0 = fmaxf(cm0, s0[i]); cm1 = fmaxf(cm1, s1[i]); }
#pragma unroll
        for (int off = 4; off > 0; off >>= 1) {
            cm0 = fmaxf(cm0, __shfl_down(cm0, off, 8));
            cm1 = fmaxf(cm1, __shfl_down(cm1, off, 8));
        }
        cm0 = __shfl(cm0, 0, 8);
        cm1 = __shfl(cm1, 0, 8);

        const float nm0 = fmaxf(m0, cm0);
        const float nm1 = fmaxf(m1, cm1);
        const float al0 = expf(m0 - nm0);
        const float al1 = expf(m1 - nm1);
        l0 *= al0; l1 *= al1;
#pragma unroll
        for (int dd = 0; dd < 32; ++dd) { o0[dd] *= al0; o1[dd] *= al1; }
        m0 = nm0; m1 = nm1;

        float p0[8], p1[8];
#pragma unroll
        for (int i = 0; i < 8; ++i) {
            p0[i] = expf(s0[i] - m0); l0 += p0[i];
            p1[i] = expf(s1[i] - m1); l1 += p1[i];
        }

#pragma unroll
        for (int i = 0; i < 8; ++i) {
            const int kk = i * 8 + lane;
#pragma unroll
            for (int dd = 0; dd < 32; dd += 4) {
                const float4 vv = *(const float4*)&Vs[kk][dd];
                o0[dd+0] = fmaf(p0[i], vv.x, o0[dd+0]);
                o0[dd+1] = fmaf(p0[i], vv.y, o0[dd+1]);
                o0[dd+2] = fmaf(p0[i], vv.z, o0[dd+2]);
                o0[dd+3] = fmaf(p0[i], vv.w, o0[dd+3]);
                o1[dd+0] = fmaf(p1[i], vv.x, o1[dd+0]);
                o1[dd+1] = fmaf(p1[i], vv.y, o1[dd+1]);
                o1[dd+2] = fmaf(p1[i], vv.z, o1[dd+2]);
                o1[dd+3] = fmaf(p1[i], vv.w, o1[dd+3]);
            }
        }
    }

#pragma unroll
    for (int off = 4; off > 0; off >>= 1) {
        l0 += __shfl_down(l0, off, 8);
        l1 += __shfl_down(l1, off, 8);
#pragma unroll
        for (int dd = 0; dd < 32; ++dd) {
            o0[dd] += __shfl_down(o0[dd], off, 8);
            o1[dd] += __shfl_down(o1[dd], off, 8);
        }
    }
    if (lane == 0) {
        const float i0 = 1.f / l0, i1 = 1.f / l1;
        float* op0 = o + ((long)(b * L_SEQ + q0) * D_MODEL + hh * DK);
        float* op1 = o + ((long)(b * L_SEQ + q1) * D_MODEL + hh * DK);
#pragma unroll
        for (int dd = 0; dd < 32; dd += 4) {
            float4 w0 = {o0[dd]*i0, o0[dd+1]*i0, o0[dd+2]*i0, o0[dd+3]*i0};
            float4 w1 = {o1[dd]*i1, o1[dd+1]*i1, o1[dd+2]*i1, o1[dd+3]*i1};
            *(float4*)&op0[dd] = w0;
            *(float4*)&op1[dd] = w1;
        }
    }
}

// ---------------------------------------------------------------------------

extern "C" void kernel_launch(void* const* d_in, const int* in_sizes, int n_in,
                              void* d_out, int out_size, void* d_ws, size_t ws_size,
                              hipStream_t stream) {
    const float* X   = (const float*)d_in[0];
    const float* MEM = (const float*)d_in[1];
    // d_in[2]/d_in[3]: boolean masks, all-true -> unused
    const float* INW = (const float*)d_in[4];
    const float* CW  = (const float*)d_in[5];
    const float* CB  = (const float*)d_in[6];
    const float* XPW = (const float*)d_in[7];
    const float* DTW = (const float*)d_in[8];
    const float* DTB = (const float*)d_in[9];
    const float* ALG = (const float*)d_in[10];
    const float* DP  = (const float*)d_in[11];
    const float* OPW = (const float*)d_in[12];
    const float* N1A = (const float*)d_in[13];
    const float* N1B = (const float*)d_in[14];
    const float* N2A = (const float*)d_in[15];
    const float* N2B = (const float*)d_in[16];
    const float* N3A = (const float*)d_in[17];
    const float* N3B = (const float*)d_in[18];
    const float* WQ  = (const float*)d_in[19];
    const float* WQB = (const float*)d_in[20];
    const float* WK  = (const float*)d_in[21];
    const float* WKB = (const float*)d_in[22];
    const float* WV  = (const float*)d_in[23];
    const float* WVB = (const float*)d_in[24];
    const float* WO  = (const float*)d_in[25];
    const float* WOB = (const float*)d_in[26];
    const float* W1  = (const float*)d_in[27];
    const float* W1B = (const float*)d_in[28];
    const float* W2  = (const float*)d_in[29];
    const float* W2B = (const float*)d_in[30];
    float* out = (float*)d_out;

    // ---- activation workspace (f32) ----
    float* p = (float*)d_ws;
    float* ln1 = p;                                  p += (long)R_TOT * D_MODEL;
    float* xz  = p;                                  p += (long)R_TOT * 2 * D_INNER;
    float* u   = p;                                  p += (long)R_TOT * D_INNER;
    float* uT  = p;                                  p += (long)R_TOT * D_INNER;
    float* dbl = p;                                  p += (long)R_TOT * DBL_LD;
    float* dtb = p;                                  p += (long)R_TOT * D_INNER;
    float* dtT = p;                                  p += (long)R_TOT * D_INNER;
    float* ysb = p;                                  p += (long)R_TOT * D_INNER;
    float* yb  = p;                                  p += (long)R_TOT * D_INNER;
    float* h1  = p;                                  p += (long)R_TOT * D_MODEL;
    float* ln2 = p;                                  p += (long)R_TOT * D_MODEL;
    float* qb  = p;                                  p += (long)R_TOT * D_MODEL;
    float* kb  = p;                                  p += (long)R_TOT * D_MODEL;
    float* vb  = p;                                  p += (long)R_TOT * D_MODEL;
    float* ao  = p;                                  p += (long)R_TOT * D_MODEL;
    float* h2  = p;                                  p += (long)R_TOT * D_MODEL;
    float* ln3 = p;                                  p += (long)R_TOT * D_MODEL;
    float* ffa = p;                                  p += (long)R_TOT * D_FF;

    const dim3 blk256(256);
    const long NE = (long)R_TOT * D_INNER;
    const int ew_grid = (int)((NE + 255) / 256);
    const dim3 tgrid(D_INNER / 64, L_SEQ / 64, B_SZ);

    // 1. ln1 = LN(x)
    ln_kernel<<<R_TOT, blk256, 0, stream>>>(X, N1A, N1B, ln1);

    // 2. xz = ln1 @ in_proj_w^T   [R,2048]
    gemm_nt<0><<<dim3(2 * D_INNER / GT, R_TOT / GT), blk256, 0, stream>>>(
        ln1, D_MODEL, INW, D_MODEL, xz, 2 * D_INNER, nullptr, nullptr,
        R_TOT, 2 * D_INNER, D_MODEL);

    // 3. u = silu(conv(xi) + conv_b)
    conv_silu_kernel<<<ew_grid, blk256, 0, stream>>>(xz, CW, CB, u);

    // 4. dbl = u @ x_proj_w^T   [R,272]
    gemm_nt<0><<<dim3((DBL_LD + GT - 1) / GT, R_TOT / GT), blk256, 0, stream>>>(
        u, D_INNER, XPW, D_INNER, dbl, DBL_LD, nullptr, nullptr,
        R_TOT, DBL_LD, D_INNER);

    // 5. dt = softplus(dbl[:, :16] @ dt_proj_w^T + dt_proj_b)   [R,1024]
    gemm_nt<2><<<dim3(D_INNER / GT, R_TOT / GT), blk256, 0, stream>>>(
        dbl, DBL_LD, DTW, DT_RANK, dtb, D_INNER, DTB, nullptr,
        R_TOT, D_INNER, DT_RANK);

    // 5b. transpose dt and u to [b][d][l] for the scan
    trans_kernel<<<tgrid, blk256, 0, stream>>>(dtb, dtT);
    trans_kernel<<<tgrid, blk256, 0, stream>>>(u, uT);

    // 6. selective scan -> ys
    scan_kernel<<<B_SZ * D_INNER, dim3(64), 0, stream>>>(dtT, uT, dbl, ALG, ysb);

    // 7. y = (ys + u*Dp) * silu(z)
    gate_kernel<<<ew_grid, blk256, 0, stream>>>(ysb, u, DP, xz, yb);

    // 8. h1 = x + y @ out_proj_w^T
    gemm_nt<0><<<dim3(D_MODEL / GT, R_TOT / GT), blk256, 0, stream>>>(
        yb, D_INNER, OPW, D_INNER, h1, D_MODEL, nullptr, X,
        R_TOT, D_MODEL, D_INNER);

    // 9. ln2 = LN(h1)
    ln_kernel<<<R_TOT, blk256, 0, stream>>>(h1, N2A, N2B, ln2);

    // 10-12. q = ln2@wq^T + b ; k,v = memory@w^T + b
    gemm_nt<0><<<dim3(D_MODEL / GT, R_TOT / GT), blk256, 0, stream>>>(
        ln2, D_MODEL, WQ, D_MODEL, qb, D_MODEL, WQB, nullptr, R_TOT, D_MODEL, D_MODEL);
    gemm_nt<0><<<dim3(D_MODEL / GT, R_TOT / GT), blk256, 0, stream>>>(
        MEM, D_MODEL, WK, D_MODEL, kb, D_MODEL, WKB, nullptr, R_TOT, D_MODEL, D_MODEL);
    gemm_nt<0><<<dim3(D_MODEL / GT, R_TOT / GT), blk256, 0, stream>>>(
        MEM, D_MODEL, WV, D_MODEL, vb, D_MODEL, WVB, nullptr, R_TOT, D_MODEL, D_MODEL);

    // 13. attention -> ao
    attn_kernel<<<dim3(L_SEQ / QT, N_HEADS, B_SZ), blk256, 0, stream>>>(qb, kb, vb, ao);

    // 14. h2 = h1 + ao @ wo^T + wo_b
    gemm_nt<0><<<dim3(D_MODEL / GT, R_TOT / GT), blk256, 0, stream>>>(
        ao, D_MODEL, WO, D_MODEL, h2, D_MODEL, WOB, h1, R_TOT, D_MODEL, D_MODEL);

    // 15. ln3 = LN(h2)
    ln_kernel<<<R_TOT, blk256, 0, stream>>>(h2, N3A, N3B, ln3);

    // 16. ffa = relu(ln3 @ w1^T + w1_b)
    gemm_nt<1><<<dim3(D_FF / GT, R_TOT / GT), blk256, 0, stream>>>(
        ln3, D_MODEL, W1, D_MODEL, ffa, D_FF, W1B, nullptr, R_TOT, D_FF, D_MODEL);

    // 17. out = h2 + ffa @ w2^T + w2_b   (f32 out)
    gemm_nt<0><<<dim3(D_MODEL / GT, R_TOT / GT), blk256, 0, stream>>>(
        ffa, D_FF, W2, D_FF, out, D_MODEL, W2B, h2, R_TOT, D_MODEL, D_FF);

    (void)in_sizes; (void)n_in; (void)out_size; (void)ws_size;
}

// Round 6
// 566.662 us; speedup vs baseline: 2.2096x; 1.7753x over previous
//
#include <hip/hip_runtime.h>
#include <hip/hip_bf16.h>

// Problem dims (fixed)
#define B_SZ 2
#define L_SEQ 512
#define D_MODEL 256
#define D_STATE 128
#define D_CONV 4
#define D_INNER 1024
#define DT_RANK 16
#define N_HEADS 8
#define DK 32
#define D_FF 1024
#define R_TOT (B_SZ * L_SEQ)   // 1024 rows
#define DBL_LD (DT_RANK + 2 * D_STATE)  // 272

typedef __hip_bfloat16 bf16;
typedef __attribute__((ext_vector_type(8))) short short8;   // 8 bf16 = 4 VGPR
typedef __attribute__((ext_vector_type(4))) float floatx4;

__device__ inline float silu_f(float x) { return x / (1.f + expf(-x)); }
__device__ inline float softplus_f(float x) { return (x > 20.f) ? x : log1pf(expf(x)); }

// ---------------------------------------------------------------------------
// Pack kernel: convert memory + 9 weight matrices f32 -> bf16 arena (1 launch)
// ---------------------------------------------------------------------------
#define S_MEM 262144
#define S_INW 524288
#define S_XPW 278528
#define S_OPW 262144
#define S_WQ  65536
#define S_WK  65536
#define S_WV  65536
#define S_WO  65536
#define S_W1  262144
#define S_W2  262144
#define S_TOT (S_MEM+S_INW+S_XPW+S_OPW+S_WQ+S_WK+S_WV+S_WO+S_W1+S_W2)

__global__ __launch_bounds__(256) void pack_bf16(
    const float* __restrict__ s0, const float* __restrict__ s1,
    const float* __restrict__ s2, const float* __restrict__ s3,
    const float* __restrict__ s4, const float* __restrict__ s5,
    const float* __restrict__ s6, const float* __restrict__ s7,
    const float* __restrict__ s8, const float* __restrict__ s9,
    bf16* __restrict__ dst)
{
    const long i = (long)blockIdx.x * 256 + threadIdx.x;
    if (i >= S_TOT) return;
    const long off[11] = {0, S_MEM, S_MEM+S_INW, S_MEM+S_INW+S_XPW,
        S_MEM+S_INW+S_XPW+S_OPW, S_MEM+S_INW+S_XPW+S_OPW+S_WQ,
        S_MEM+S_INW+S_XPW+S_OPW+S_WQ+S_WK,
        S_MEM+S_INW+S_XPW+S_OPW+S_WQ+S_WK+S_WV,
        S_MEM+S_INW+S_XPW+S_OPW+S_WQ+S_WK+S_WV+S_WO,
        S_MEM+S_INW+S_XPW+S_OPW+S_WQ+S_WK+S_WV+S_WO+S_W1, S_TOT};
    const float* srcs[10] = {s0,s1,s2,s3,s4,s5,s6,s7,s8,s9};
    int seg = 0;
#pragma unroll
    for (int k = 1; k < 10; ++k) if (i >= off[k]) seg = k;
    dst[i] = __float2bfloat16(srcs[seg][i - off[seg]]);
}

// ---------------------------------------------------------------------------
// MFMA GEMM: C[M,N] = epi( A[M,K] @ W[N,K]^T + bias ) (+res).  A,W bf16.
// Block 256 thr = 4 waves; block tile 64(M)x64(N); wave w owns rows w*16..+15.
// Direct-global fragment loads (A row: 16B/lane; W tile shared by all waves).
// Layouts (HW-verified): A/B lane holds 8 contig k at row=lane&15,
// k0+(lane>>4)*8 ; C/D col=lane&15, row=(lane>>4)*4+reg.
// EPI: 0=none, 1=relu. Writes f32 C and/or bf16 Cb (either may be null).
// ---------------------------------------------------------------------------
template <int EPI>
__global__ __launch_bounds__(256) void mfma_gemm(
    const bf16* __restrict__ A, const bf16* __restrict__ W, int K,
    float* __restrict__ C, bf16* __restrict__ Cb, int ldc,
    const float* __restrict__ bias, const float* __restrict__ res,
    int M, int N)
{
    const int wave = threadIdx.x >> 6;
    const int lane = threadIdx.x & 63;
    const int row16 = lane & 15;
    const int quad  = lane >> 4;
    const int bm = blockIdx.y * 64 + wave * 16;
    const int bn = blockIdx.x * 64;

    floatx4 acc[4];
#pragma unroll
    for (int t = 0; t < 4; ++t) acc[t] = (floatx4){0.f, 0.f, 0.f, 0.f};

    const long arow = (long)(bm + row16) * K;
    for (int k0 = 0; k0 < K; k0 += 32) {
        const short8 av = *(const short8*)(A + arow + k0 + quad * 8);
#pragma unroll
        for (int t = 0; t < 4; ++t) {
            const int gn = bn + t * 16 + row16;
            short8 bv = {0,0,0,0,0,0,0,0};
            if (gn < N) bv = *(const short8*)(W + (long)gn * K + k0 + quad * 8);
            acc[t] = __builtin_amdgcn_mfma_f32_16x16x32_bf16(av, bv, acc[t], 0, 0, 0);
        }
    }

#pragma unroll
    for (int t = 0; t < 4; ++t) {
        const int gn = bn + t * 16 + row16;
        if (gn >= N) continue;
        const float bs = bias ? bias[gn] : 0.f;
#pragma unroll
        for (int r = 0; r < 4; ++r) {
            const int gm = bm + quad * 4 + r;
            float v = acc[t][r] + bs;
            if (EPI == 1) v = fmaxf(v, 0.f);
            const long ci = (long)gm * ldc + gn;
            if (res) v += res[ci];
            if (C)  C[ci] = v;
            if (Cb) Cb[ci] = __float2bfloat16(v);
        }
    }
}

// ---------------------------------------------------------------------------
// f32 GEMM (used only for dt_proj, K=16, softplus epi)
// ---------------------------------------------------------------------------
#define GT 64
#define GK 16

template <int EPI>
__global__ __launch_bounds__(256) void gemm_nt(
    const float* __restrict__ A, int lda,
    const float* __restrict__ W, int ldb,
    float* __restrict__ C, int ldc,
    const float* __restrict__ bias,
    const float* __restrict__ res,
    int M, int N, int K)
{
    __shared__ float As[GK][GT + 1];
    __shared__ float Bs[GK][GT + 1];

    const int bm = blockIdx.y * GT;
    const int bn = blockIdx.x * GT;
    const int tid = threadIdx.x;
    const int tx = tid & 15;
    const int ty = tid >> 4;

    float acc[4][4] = {};

    for (int k0 = 0; k0 < K; k0 += GK) {
        const int r = tid >> 2;
        const int kk = (tid & 3) * 4;
        const int gm = bm + r;
        const int gn = bn + r;
#pragma unroll
        for (int q = 0; q < 4; ++q) {
            const int gk = k0 + kk + q;
            As[kk + q][r] = (gm < M && gk < K) ? A[(long)gm * lda + gk] : 0.f;
            Bs[kk + q][r] = (gn < N && gk < K) ? W[(long)gn * ldb + gk] : 0.f;
        }
        __syncthreads();
#pragma unroll
        for (int k = 0; k < GK; ++k) {
            float a[4], b[4];
#pragma unroll
            for (int i = 0; i < 4; ++i) a[i] = As[k][ty * 4 + i];
#pragma unroll
            for (int j = 0; j < 4; ++j) b[j] = Bs[k][tx * 4 + j];
#pragma unroll
            for (int i = 0; i < 4; ++i)
#pragma unroll
                for (int j = 0; j < 4; ++j)
                    acc[i][j] = fmaf(a[i], b[j], acc[i][j]);
        }
        __syncthreads();
    }

#pragma unroll
    for (int i = 0; i < 4; ++i) {
        const int gm = bm + ty * 4 + i;
        if (gm >= M) continue;
#pragma unroll
        for (int j = 0; j < 4; ++j) {
            const int gn = bn + tx * 4 + j;
            if (gn >= N) continue;
            float v = acc[i][j];
            if (bias) v += bias[gn];
            if (EPI == 1) v = fmaxf(v, 0.f);
            if (EPI == 2) v = softplus_f(v);
            const long ci = (long)gm * ldc + gn;
            if (res) v += res[ci];
            C[ci] = v;
        }
    }
}

// ---------------------------------------------------------------------------
// LayerNorm -> bf16 output (all LN outputs feed only MFMA GEMMs)
// ---------------------------------------------------------------------------
__global__ __launch_bounds__(256) void ln_kernel(
    const float* __restrict__ x, const float* __restrict__ a,
    const float* __restrict__ bvec, bf16* __restrict__ out)
{
    const int row = blockIdx.x;
    const int t = threadIdx.x;
    const float v = x[(long)row * D_MODEL + t];
    __shared__ float r1[256], r2[256];
    r1[t] = v;
    r2[t] = v * v;
    __syncthreads();
    for (int s = 128; s > 0; s >>= 1) {
        if (t < s) { r1[t] += r1[t + s]; r2[t] += r2[t + s]; }
        __syncthreads();
    }
    const float mean = r1[0] * (1.f / 256.f);
    const float var = (r2[0] - 256.f * mean * mean) * (1.f / 255.f);
    const float sd = sqrtf(fmaxf(var, 0.f));
    const float o = a[t] * (v - mean) / (sd + 1e-6f) + bvec[t];
    out[(long)row * D_MODEL + t] = __float2bfloat16(o);
}

// ---------------------------------------------------------------------------
// Causal depthwise conv (k=4) + SiLU -> u (f32) + ub (bf16)
// ---------------------------------------------------------------------------
__global__ __launch_bounds__(256) void conv_silu_kernel(
    const float* __restrict__ xz, const float* __restrict__ cw,
    const float* __restrict__ cb, float* __restrict__ u, bf16* __restrict__ ub)
{
    const long i = (long)blockIdx.x * 256 + threadIdx.x;
    if (i >= (long)R_TOT * D_INNER) return;
    const int d = (int)(i % D_INNER);
    const long row = i / D_INNER;
    const int l = (int)(row % L_SEQ);
    const long b = row / L_SEQ;
    float s = cb[d];
#pragma unroll
    for (int k = 0; k < D_CONV; ++k) {
        const int ls = l - (D_CONV - 1) + k;
        if (ls >= 0)
            s += xz[((b * L_SEQ + ls) * (2 * D_INNER)) + d] * cw[d * D_CONV + k];
    }
    const float r = silu_f(s);
    u[i] = r;
    ub[i] = __float2bfloat16(r);
}

// ---------------------------------------------------------------------------
// Transpose per batch: [B*L][1024] -> [B][1024][512]
// ---------------------------------------------------------------------------
__global__ __launch_bounds__(256) void trans_kernel(
    const float* __restrict__ in, float* __restrict__ out)
{
    __shared__ float t[64][65];
    const int db = blockIdx.x;
    const int lb = blockIdx.y;
    const int b  = blockIdx.z;
    const int tid = threadIdx.x;
    const int r  = tid >> 4;
    const int c4 = (tid & 15) * 4;

#pragma unroll
    for (int q = 0; q < 4; ++q) {
        const int lr = r + q * 16;
        const float4 v = *(const float4*)&in[((long)(b * L_SEQ + lb * 64 + lr)) * D_INNER + db * 64 + c4];
        t[lr][c4 + 0] = v.x; t[lr][c4 + 1] = v.y;
        t[lr][c4 + 2] = v.z; t[lr][c4 + 3] = v.w;
    }
    __syncthreads();
#pragma unroll
    for (int q = 0; q < 4; ++q) {
        const int dr = r + q * 16;
        float4 v;
        v.x = t[c4 + 0][dr]; v.y = t[c4 + 1][dr];
        v.z = t[c4 + 2][dr]; v.w = t[c4 + 3][dr];
        *(float4*)&out[((long)(b * D_INNER + db * 64 + dr)) * L_SEQ + lb * 64 + c4] = v;
    }
}

// ---------------------------------------------------------------------------
// Selective scan v3 (unchanged from round 5)
// ---------------------------------------------------------------------------
__global__ __launch_bounds__(64) void scan_kernel(
    const float* __restrict__ dtT, const float* __restrict__ uT,
    const float* __restrict__ dbl, const float* __restrict__ A_log,
    float* __restrict__ ys)
{
    const int blk = blockIdx.x;
    const int b = blk >> 10;
    const int d = blk & 1023;
    const int lane = threadIdx.x;
    const int n0 = lane * 2;

    const float An0 = -expf(A_log[(long)d * D_STATE + n0]);
    const float An1 = -expf(A_log[(long)d * D_STATE + n0 + 1]);
    float h0 = 0.f, h1 = 0.f;

    const float* dtp = dtT + ((long)(b * D_INNER + d) << 9);
    const float* up  = uT  + ((long)(b * D_INNER + d) << 9);
    const float* blp = dbl + (long)b * L_SEQ * DBL_LD + DT_RANK + n0;
    const float* clp = blp + D_STATE;
    float* ysp = ys + ((long)b * L_SEQ) * D_INNER + d;

    float4 dtc0 = *(const float4*)(dtp);
    float4 dtc1 = *(const float4*)(dtp + 4);
    float4 uc0  = *(const float4*)(up);
    float4 uc1  = *(const float4*)(up + 4);
    float2 Bc[8], Cc[8];
#pragma unroll
    for (int j = 0; j < 8; ++j) {
        Bc[j] = *(const float2*)(blp + (long)j * DBL_LD);
        Cc[j] = *(const float2*)(clp + (long)j * DBL_LD);
    }

    for (int s = 0; s < L_SEQ / 8; ++s) {
        const int nb = (s + 1) & (L_SEQ / 8 - 1);
        const float4 dtn0 = *(const float4*)(dtp + nb * 8);
        const float4 dtn1 = *(const float4*)(dtp + nb * 8 + 4);
        const float4 un0  = *(const float4*)(up + nb * 8);
        const float4 un1  = *(const float4*)(up + nb * 8 + 4);
        float2 Bn[8], Cn[8];
#pragma unroll
        for (int j = 0; j < 8; ++j) {
            Bn[j] = *(const float2*)(blp + (long)(nb * 8 + j) * DBL_LD);
            Cn[j] = *(const float2*)(clp + (long)(nb * 8 + j) * DBL_LD);
        }

        const float dts[8] = {dtc0.x, dtc0.y, dtc0.z, dtc0.w, dtc1.x, dtc1.y, dtc1.z, dtc1.w};
        const float us[8]  = {uc0.x,  uc0.y,  uc0.z,  uc0.w,  uc1.x,  uc1.y,  uc1.z,  uc1.w};
#pragma unroll
        for (int j = 0; j < 8; ++j) {
            const float dtv = dts[j];
            const float dtu = dtv * us[j];
            const float dA0 = expf(dtv * An0);
            const float dA1 = expf(dtv * An1);
            h0 = fmaf(dA0, h0, dtu * Bc[j].x);
            h1 = fmaf(dA1, h1, dtu * Bc[j].y);
            float yp = fmaf(h0, Cc[j].x, h1 * Cc[j].y);
#pragma unroll
            for (int off = 32; off > 0; off >>= 1) yp += __shfl_down(yp, off);
            if (lane == 0) ysp[(long)(s * 8 + j) * D_INNER] = yp;
        }

        dtc0 = dtn0; dtc1 = dtn1; uc0 = un0; uc1 = un1;
#pragma unroll
        for (int j = 0; j < 8; ++j) { Bc[j] = Bn[j]; Cc[j] = Cn[j]; }
    }
}

// ---------------------------------------------------------------------------
// y = (ys + u*Dp) * silu(z)  -> bf16 (feeds out_proj MFMA only)
// ---------------------------------------------------------------------------
__global__ __launch_bounds__(256) void gate_kernel(
    const float* __restrict__ ys, const float* __restrict__ u,
    const float* __restrict__ Dp, const float* __restrict__ xz,
    bf16* __restrict__ y)
{
    const long i = (long)blockIdx.x * 256 + threadIdx.x;
    if (i >= (long)R_TOT * D_INNER) return;
    const int d = (int)(i % D_INNER);
    const long row = i / D_INNER;
    const float z = xz[row * (2 * D_INNER) + D_INNER + d];
    y[i] = __float2bfloat16((ys[i] + u[i] * Dp[d]) * silu_f(z));
}

// ---------------------------------------------------------------------------
// Flash-style cross-attention -> bf16 output (feeds wo MFMA only)
// ---------------------------------------------------------------------------
#define QT 64
#define CK 64

__global__ __launch_bounds__(256) void attn_kernel(
    const float* __restrict__ q, const float* __restrict__ k,
    const float* __restrict__ v, bf16* __restrict__ o)
{
    const int qt = blockIdx.x;
    const int hh = blockIdx.y;
    const int b  = blockIdx.z;
    const int t = threadIdx.x;
    const int lane = t & 7;
    const int qa = t >> 3;
    const int q0 = qt * QT + qa;
    const int q1 = q0 + 32;

    __shared__ float Ks[CK][36];
    __shared__ float Vs[CK][36];

    const float scale = 0.17677669529663687f;
    float qr0[32], qr1[32];
    {
        const float* q0p = q + ((long)(b * L_SEQ + q0) * D_MODEL + hh * DK);
        const float* q1p = q + ((long)(b * L_SEQ + q1) * D_MODEL + hh * DK);
#pragma unroll
        for (int i = 0; i < 8; ++i) {
            const float4 a = *(const float4*)&q0p[i * 4];
            const float4 c = *(const float4*)&q1p[i * 4];
            qr0[i*4+0] = a.x * scale; qr0[i*4+1] = a.y * scale;
            qr0[i*4+2] = a.z * scale; qr0[i*4+3] = a.w * scale;
            qr1[i*4+0] = c.x * scale; qr1[i*4+1] = c.y * scale;
            qr1[i*4+2] = c.z * scale; qr1[i*4+3] = c.w * scale;
        }
    }

    float m0 = -1e30f, l0 = 0.f, o0[32] = {};
    float m1 = -1e30f, l1 = 0.f, o1[32] = {};

    for (int c = 0; c < L_SEQ; c += CK) {
        __syncthreads();
        {
            const int fid = t * 2;
            const int row = fid >> 3;
            const int c0  = (fid & 7) * 4;
            const float* kp = k + ((long)(b * L_SEQ + c + row) * D_MODEL + hh * DK + c0);
            const float* vp = v + ((long)(b * L_SEQ + c + row) * D_MODEL + hh * DK + c0);
            *(float4*)&Ks[row][c0]     = *(const float4*)kp;
            *(float4*)&Ks[row][c0 + 4] = *(const float4*)(kp + 4);
            *(float4*)&Vs[row][c0]     = *(const float4*)vp;
            *(float4*)&Vs[row][c0 + 4] = *(const float4*)(vp + 4);
        }
        __syncthreads();

        float s0[8], s1[8];
#pragma unroll
        for (int i = 0; i < 8; ++i) {
            const int kk = i * 8 + lane;
            float a0 = 0.f, a1 = 0.f;
#pragma unroll
            for (int dd = 0; dd < 32; dd += 4) {
                const float4 kv = *(const float4*)&Ks[kk][dd];
                a0 = fmaf(qr0[dd+0], kv.x, a0); a0 = fmaf(qr0[dd+1], kv.y, a0);
                a0 = fmaf(qr0[dd+2], kv.z, a0); a0 = fmaf(qr0[dd+3], kv.w, a0);
                a1 = fmaf(qr1[dd+0], kv.x, a1); a1 = fmaf(qr1[dd+1], kv.y, a1);
                a1 = fmaf(qr1[dd+2], kv.z, a1); a1 = fmaf(qr1[dd+3], kv.w, a1);
            }
            s0[i] = a0; s1[i] = a1;
        }

        float cm0 = s0[0], cm1 = s1[0];
#pragma unroll
        for (int i = 1; i < 8; ++i) { cm0 = fmaxf(cm0, s0[i]); cm1 = fmaxf(cm1, s1[i]); }
#pragma unroll
        for (int off = 4; off > 0; off >>= 1) {
            cm0 = fmaxf(cm0, __shfl_down(cm0, off, 8));
            cm1 = fmaxf(cm1, __shfl_down(cm1, off, 8));
        }
        cm0 = __shfl(cm0, 0, 8);
        cm1 = __shfl(cm1, 0, 8);

        const float nm0 = fmaxf(m0, cm0);
        const float nm1 = fmaxf(m1, cm1);
        const float al0 = expf(m0 - nm0);
        const float al1 = expf(m1 - nm1);
        l0 *= al0; l1 *= al1;
#pragma unroll
        for (int dd = 0; dd < 32; ++dd) { o0[dd] *= al0; o1[dd] *= al1; }
        m0 = nm0; m1 = nm1;

        float p0[8], p1[8];
#pragma unroll
        for (int i = 0; i < 8; ++i) {
            p0[i] = expf(s0[i] - m0); l0 += p0[i];
            p1[i] = expf(s1[i] - m1); l1 += p1[i];
        }

#pragma unroll
        for (int i = 0; i < 8; ++i) {
            const int kk = i * 8 + lane;
#pragma unroll
            for (int dd = 0; dd < 32; dd += 4) {
                const float4 vv = *(const float4*)&Vs[kk][dd];
                o0[dd+0] = fmaf(p0[i], vv.x, o0[dd+0]);
                o0[dd+1] = fmaf(p0[i], vv.y, o0[dd+1]);
                o0[dd+2] = fmaf(p0[i], vv.z, o0[dd+2]);
                o0[dd+3] = fmaf(p0[i], vv.w, o0[dd+3]);
                o1[dd+0] = fmaf(p1[i], vv.x, o1[dd+0]);
                o1[dd+1] = fmaf(p1[i], vv.y, o1[dd+1]);
                o1[dd+2] = fmaf(p1[i], vv.z, o1[dd+2]);
                o1[dd+3] = fmaf(p1[i], vv.w, o1[dd+3]);
            }
        }
    }

#pragma unroll
    for (int off = 4; off > 0; off >>= 1) {
        l0 += __shfl_down(l0, off, 8);
        l1 += __shfl_down(l1, off, 8);
#pragma unroll
        for (int dd = 0; dd < 32; ++dd) {
            o0[dd] += __shfl_down(o0[dd], off, 8);
            o1[dd] += __shfl_down(o1[dd], off, 8);
        }
    }
    if (lane == 0) {
        const float i0 = 1.f / l0, i1 = 1.f / l1;
        bf16* op0 = o + ((long)(b * L_SEQ + q0) * D_MODEL + hh * DK);
        bf16* op1 = o + ((long)(b * L_SEQ + q1) * D_MODEL + hh * DK);
#pragma unroll
        for (int dd = 0; dd < 32; ++dd) {
            op0[dd] = __float2bfloat16(o0[dd] * i0);
            op1[dd] = __float2bfloat16(o1[dd] * i1);
        }
    }
}

// ---------------------------------------------------------------------------

extern "C" void kernel_launch(void* const* d_in, const int* in_sizes, int n_in,
                              void* d_out, int out_size, void* d_ws, size_t ws_size,
                              hipStream_t stream) {
    const float* X   = (const float*)d_in[0];
    const float* MEM = (const float*)d_in[1];
    const float* INW = (const float*)d_in[4];
    const float* CW  = (const float*)d_in[5];
    const float* CB  = (const float*)d_in[6];
    const float* XPW = (const float*)d_in[7];
    const float* DTW = (const float*)d_in[8];
    const float* DTB = (const float*)d_in[9];
    const float* ALG = (const float*)d_in[10];
    const float* DP  = (const float*)d_in[11];
    const float* OPW = (const float*)d_in[12];
    const float* N1A = (const float*)d_in[13];
    const float* N1B = (const float*)d_in[14];
    const float* N2A = (const float*)d_in[15];
    const float* N2B = (const float*)d_in[16];
    const float* N3A = (const float*)d_in[17];
    const float* N3B = (const float*)d_in[18];
    const float* WQ  = (const float*)d_in[19];
    const float* WQB = (const float*)d_in[20];
    const float* WKw = (const float*)d_in[21];
    const float* WKB = (const float*)d_in[22];
    const float* WVw = (const float*)d_in[23];
    const float* WVB = (const float*)d_in[24];
    const float* WO  = (const float*)d_in[25];
    const float* WOB = (const float*)d_in[26];
    const float* W1  = (const float*)d_in[27];
    const float* W1B = (const float*)d_in[28];
    const float* W2  = (const float*)d_in[29];
    const float* W2B = (const float*)d_in[30];
    float* out = (float*)d_out;

    // ---- bf16 arena first (16B-aligned at ws base) ----
    bf16* bp = (bf16*)d_ws;
    bf16* ub   = bp;  bp += (long)R_TOT * D_INNER;      // conv out
    bf16* ybb  = bp;  bp += (long)R_TOT * D_INNER;      // gate out; alias: ffab
    bf16* ffab = ybb;                                   // w1 out (ybb dead by then)
    bf16* ln1b = bp;  bp += (long)R_TOT * D_MODEL;      // alias: aob
    bf16* aob  = ln1b;                                  // attn out (ln1b dead)
    bf16* ln2b = bp;  bp += (long)R_TOT * D_MODEL;      // alias: ln3b
    bf16* ln3b = ln2b;
    bf16* arena = bp; bp += S_TOT;                      // packed weights + MEM
    bf16* MEMb = arena;
    bf16* INWb = MEMb + S_MEM;
    bf16* XPWb = INWb + S_INW;
    bf16* OPWb = XPWb + S_XPW;
    bf16* WQb  = OPWb + S_OPW;
    bf16* WKb  = WQb + S_WQ;
    bf16* WVb  = WKb + S_WK;
    bf16* WOb  = WVb + S_WV;
    bf16* W1b  = WOb + S_WO;
    bf16* W2b  = W1b + S_W1;

    // ---- f32 buffers ----
    float* p = (float*)(bp + ((((long)(bp - (bf16*)d_ws)) & 1) ? 1 : 0)); // keep 4B align
    float* xz  = p;                                  p += (long)R_TOT * 2 * D_INNER;
    float* u   = p;                                  p += (long)R_TOT * D_INNER;
    float* uT  = p;                                  p += (long)R_TOT * D_INNER;
    float* dbl = p;                                  p += (long)R_TOT * DBL_LD;
    float* dtb = p;                                  p += (long)R_TOT * D_INNER;   // alias: ysb
    float* ysb = dtb;                                                              // scan out (dtb dead)
    float* dtT = p;                                  p += (long)R_TOT * D_INNER;
    float* h1  = p;                                  p += (long)R_TOT * D_MODEL;
    float* qb  = p;                                  p += (long)R_TOT * D_MODEL;
    float* kb  = p;                                  p += (long)R_TOT * D_MODEL;
    float* vb  = p;                                  p += (long)R_TOT * D_MODEL;
    float* h2  = p;                                  p += (long)R_TOT * D_MODEL;

    const dim3 blk256(256);
    const long NE = (long)R_TOT * D_INNER;
    const int ew_grid = (int)((NE + 255) / 256);
    const dim3 tgrid(D_INNER / 64, L_SEQ / 64, B_SZ);
    const int MT64 = R_TOT / 64;   // 16

    // 0. pack weights + memory to bf16
    pack_bf16<<<(S_TOT + 255) / 256, blk256, 0, stream>>>(
        MEM, INW, XPW, OPW, WQ, WKw, WVw, WO, W1, W2, arena);

    // 1. ln1 = LN(x) -> bf16
    ln_kernel<<<R_TOT, blk256, 0, stream>>>(X, N1A, N1B, ln1b);

    // 2. xz = ln1 @ in_proj^T   [R,2048] f32
    mfma_gemm<0><<<dim3(2 * D_INNER / 64, MT64), blk256, 0, stream>>>(
        ln1b, INWb, D_MODEL, xz, nullptr, 2 * D_INNER, nullptr, nullptr,
        R_TOT, 2 * D_INNER);

    // 3. u = silu(conv(xi)+cb) -> f32 + bf16
    conv_silu_kernel<<<ew_grid, blk256, 0, stream>>>(xz, CW, CB, u, ub);

    // 4. dbl = u @ x_proj^T   [R,272] f32
    mfma_gemm<0><<<dim3((DBL_LD + 63) / 64, MT64), blk256, 0, stream>>>(
        ub, XPWb, D_INNER, dbl, nullptr, DBL_LD, nullptr, nullptr,
        R_TOT, DBL_LD);

    // 5. dt = softplus(dbl[:,:16] @ dt_proj^T + b)  (f32 path, K=16)
    gemm_nt<2><<<dim3(D_INNER / GT, R_TOT / GT), blk256, 0, stream>>>(
        dbl, DBL_LD, DTW, DT_RANK, dtb, D_INNER, DTB, nullptr,
        R_TOT, D_INNER, DT_RANK);

    // 5b. transposes for scan
    trans_kernel<<<tgrid, blk256, 0, stream>>>(dtb, dtT);
    trans_kernel<<<tgrid, blk256, 0, stream>>>(u, uT);

    // 6. selective scan -> ys (aliases dtb; dtb consumed by trans above)
    scan_kernel<<<B_SZ * D_INNER, dim3(64), 0, stream>>>(dtT, uT, dbl, ALG, ysb);

    // 7. y = (ys + u*Dp)*silu(z) -> bf16
    gate_kernel<<<ew_grid, blk256, 0, stream>>>(ysb, u, DP, xz, ybb);

    // 8. h1 = x + y @ out_proj^T  f32
    mfma_gemm<0><<<dim3(D_MODEL / 64, MT64), blk256, 0, stream>>>(
        ybb, OPWb, D_INNER, h1, nullptr, D_MODEL, nullptr, X,
        R_TOT, D_MODEL);

    // 9. ln2 -> bf16
    ln_kernel<<<R_TOT, blk256, 0, stream>>>(h1, N2A, N2B, ln2b);

    // 10-12. q,k,v
    mfma_gemm<0><<<dim3(D_MODEL / 64, MT64), blk256, 0, stream>>>(
        ln2b, WQb, D_MODEL, qb, nullptr, D_MODEL, WQB, nullptr, R_TOT, D_MODEL);
    mfma_gemm<0><<<dim3(D_MODEL / 64, MT64), blk256, 0, stream>>>(
        MEMb, WKb, D_MODEL, kb, nullptr, D_MODEL, WKB, nullptr, R_TOT, D_MODEL);
    mfma_gemm<0><<<dim3(D_MODEL / 64, MT64), blk256, 0, stream>>>(
        MEMb, WVb, D_MODEL, vb, nullptr, D_MODEL, WVB, nullptr, R_TOT, D_MODEL);

    // 13. attention -> bf16
    attn_kernel<<<dim3(L_SEQ / QT, N_HEADS, B_SZ), blk256, 0, stream>>>(qb, kb, vb, aob);

    // 14. h2 = h1 + ao @ wo^T + wo_b  f32
    mfma_gemm<0><<<dim3(D_MODEL / 64, MT64), blk256, 0, stream>>>(
        aob, WOb, D_MODEL, h2, nullptr, D_MODEL, WOB, h1, R_TOT, D_MODEL);

    // 15. ln3 -> bf16
    ln_kernel<<<R_TOT, blk256, 0, stream>>>(h2, N3A, N3B, ln3b);

    // 16. ffa = relu(ln3 @ w1^T + b) -> bf16 only
    mfma_gemm<1><<<dim3(D_FF / 64, MT64), blk256, 0, stream>>>(
        ln3b, W1b, D_MODEL, nullptr, ffab, D_FF, W1B, nullptr, R_TOT, D_FF);

    // 17. out = h2 + ffa @ w2^T + b  f32
    mfma_gemm<0><<<dim3(D_MODEL / 64, MT64), blk256, 0, stream>>>(
        ffab, W2b, D_FF, out, nullptr, D_MODEL, W2B, h2, R_TOT, D_MODEL);

    (void)in_sizes; (void)n_in; (void)out_size; (void)ws_size;
}

// Round 7
// 530.208 us; speedup vs baseline: 2.3615x; 1.0688x over previous
//
#include <hip/hip_runtime.h>
#include <hip/hip_bf16.h>

// Problem dims (fixed)
#define B_SZ 2
#define L_SEQ 512
#define D_MODEL 256
#define D_STATE 128
#define D_CONV 4
#define D_INNER 1024
#define DT_RANK 16
#define N_HEADS 8
#define DK 32
#define D_FF 1024
#define R_TOT (B_SZ * L_SEQ)   // 1024 rows
#define DBL_LD (DT_RANK + 2 * D_STATE)  // 272

typedef __hip_bfloat16 bf16;
typedef __attribute__((ext_vector_type(8))) short short8;   // 8 bf16 = 4 VGPR
typedef __attribute__((ext_vector_type(4))) float floatx4;

__device__ inline float silu_f(float x) { return x / (1.f + expf(-x)); }
__device__ inline float softplus_f(float x) { return (x > 20.f) ? x : log1pf(expf(x)); }

// ---------------------------------------------------------------------------
// Pack kernel: convert memory + 9 weight matrices f32 -> bf16 arena (1 launch)
// ---------------------------------------------------------------------------
#define S_MEM 262144
#define S_INW 524288
#define S_XPW 278528
#define S_OPW 262144
#define S_WQ  65536
#define S_WK  65536
#define S_WV  65536
#define S_WO  65536
#define S_W1  262144
#define S_W2  262144
#define S_TOT (S_MEM+S_INW+S_XPW+S_OPW+S_WQ+S_WK+S_WV+S_WO+S_W1+S_W2)

__global__ __launch_bounds__(256) void pack_bf16(
    const float* __restrict__ s0, const float* __restrict__ s1,
    const float* __restrict__ s2, const float* __restrict__ s3,
    const float* __restrict__ s4, const float* __restrict__ s5,
    const float* __restrict__ s6, const float* __restrict__ s7,
    const float* __restrict__ s8, const float* __restrict__ s9,
    bf16* __restrict__ dst)
{
    const long i = (long)blockIdx.x * 256 + threadIdx.x;
    if (i >= S_TOT) return;
    const long off[11] = {0, S_MEM, S_MEM+S_INW, S_MEM+S_INW+S_XPW,
        S_MEM+S_INW+S_XPW+S_OPW, S_MEM+S_INW+S_XPW+S_OPW+S_WQ,
        S_MEM+S_INW+S_XPW+S_OPW+S_WQ+S_WK,
        S_MEM+S_INW+S_XPW+S_OPW+S_WQ+S_WK+S_WV,
        S_MEM+S_INW+S_XPW+S_OPW+S_WQ+S_WK+S_WV+S_WO,
        S_MEM+S_INW+S_XPW+S_OPW+S_WQ+S_WK+S_WV+S_WO+S_W1, S_TOT};
    const float* srcs[10] = {s0,s1,s2,s3,s4,s5,s6,s7,s8,s9};
    int seg = 0;
#pragma unroll
    for (int k = 1; k < 10; ++k) if (i >= off[k]) seg = k;
    dst[i] = __float2bfloat16(srcs[seg][i - off[seg]]);
}

// ---------------------------------------------------------------------------
// MFMA GEMM (unchanged from round 6): C = epi(A @ W^T + bias)(+res), bf16 in.
// ---------------------------------------------------------------------------
template <int EPI>
__global__ __launch_bounds__(256) void mfma_gemm(
    const bf16* __restrict__ A, const bf16* __restrict__ W, int K,
    float* __restrict__ C, bf16* __restrict__ Cb, int ldc,
    const float* __restrict__ bias, const float* __restrict__ res,
    int M, int N)
{
    const int wave = threadIdx.x >> 6;
    const int lane = threadIdx.x & 63;
    const int row16 = lane & 15;
    const int quad  = lane >> 4;
    const int bm = blockIdx.y * 64 + wave * 16;
    const int bn = blockIdx.x * 64;

    floatx4 acc[4];
#pragma unroll
    for (int t = 0; t < 4; ++t) acc[t] = (floatx4){0.f, 0.f, 0.f, 0.f};

    const long arow = (long)(bm + row16) * K;
    for (int k0 = 0; k0 < K; k0 += 32) {
        const short8 av = *(const short8*)(A + arow + k0 + quad * 8);
#pragma unroll
        for (int t = 0; t < 4; ++t) {
            const int gn = bn + t * 16 + row16;
            short8 bv = {0,0,0,0,0,0,0,0};
            if (gn < N) bv = *(const short8*)(W + (long)gn * K + k0 + quad * 8);
            acc[t] = __builtin_amdgcn_mfma_f32_16x16x32_bf16(av, bv, acc[t], 0, 0, 0);
        }
    }

#pragma unroll
    for (int t = 0; t < 4; ++t) {
        const int gn = bn + t * 16 + row16;
        if (gn >= N) continue;
        const float bs = bias ? bias[gn] : 0.f;
#pragma unroll
        for (int r = 0; r < 4; ++r) {
            const int gm = bm + quad * 4 + r;
            float v = acc[t][r] + bs;
            if (EPI == 1) v = fmaxf(v, 0.f);
            const long ci = (long)gm * ldc + gn;
            if (res) v += res[ci];
            if (C)  C[ci] = v;
            if (Cb) Cb[ci] = __float2bfloat16(v);
        }
    }
}

// ---------------------------------------------------------------------------
// f32 GEMM (dt_proj only, K=16, softplus epi)
// ---------------------------------------------------------------------------
#define GT 64
#define GK 16

template <int EPI>
__global__ __launch_bounds__(256) void gemm_nt(
    const float* __restrict__ A, int lda,
    const float* __restrict__ W, int ldb,
    float* __restrict__ C, int ldc,
    const float* __restrict__ bias,
    const float* __restrict__ res,
    int M, int N, int K)
{
    __shared__ float As[GK][GT + 1];
    __shared__ float Bs[GK][GT + 1];

    const int bm = blockIdx.y * GT;
    const int bn = blockIdx.x * GT;
    const int tid = threadIdx.x;
    const int tx = tid & 15;
    const int ty = tid >> 4;

    float acc[4][4] = {};

    for (int k0 = 0; k0 < K; k0 += GK) {
        const int r = tid >> 2;
        const int kk = (tid & 3) * 4;
        const int gm = bm + r;
        const int gn = bn + r;
#pragma unroll
        for (int q = 0; q < 4; ++q) {
            const int gk = k0 + kk + q;
            As[kk + q][r] = (gm < M && gk < K) ? A[(long)gm * lda + gk] : 0.f;
            Bs[kk + q][r] = (gn < N && gk < K) ? W[(long)gn * ldb + gk] : 0.f;
        }
        __syncthreads();
#pragma unroll
        for (int k = 0; k < GK; ++k) {
            float a[4], b[4];
#pragma unroll
            for (int i = 0; i < 4; ++i) a[i] = As[k][ty * 4 + i];
#pragma unroll
            for (int j = 0; j < 4; ++j) b[j] = Bs[k][tx * 4 + j];
#pragma unroll
            for (int i = 0; i < 4; ++i)
#pragma unroll
                for (int j = 0; j < 4; ++j)
                    acc[i][j] = fmaf(a[i], b[j], acc[i][j]);
        }
        __syncthreads();
    }

#pragma unroll
    for (int i = 0; i < 4; ++i) {
        const int gm = bm + ty * 4 + i;
        if (gm >= M) continue;
#pragma unroll
        for (int j = 0; j < 4; ++j) {
            const int gn = bn + tx * 4 + j;
            if (gn >= N) continue;
            float v = acc[i][j];
            if (bias) v += bias[gn];
            if (EPI == 1) v = fmaxf(v, 0.f);
            if (EPI == 2) v = softplus_f(v);
            const long ci = (long)gm * ldc + gn;
            if (res) v += res[ci];
            C[ci] = v;
        }
    }
}

// ---------------------------------------------------------------------------
// LayerNorm -> bf16 (reference semantics: var/(d-1), denom std+eps)
// ---------------------------------------------------------------------------
__global__ __launch_bounds__(256) void ln_kernel(
    const float* __restrict__ x, const float* __restrict__ a,
    const float* __restrict__ bvec, bf16* __restrict__ out)
{
    const int row = blockIdx.x;
    const int t = threadIdx.x;
    const float v = x[(long)row * D_MODEL + t];
    __shared__ float r1[256], r2[256];
    r1[t] = v;
    r2[t] = v * v;
    __syncthreads();
    for (int s = 128; s > 0; s >>= 1) {
        if (t < s) { r1[t] += r1[t + s]; r2[t] += r2[t + s]; }
        __syncthreads();
    }
    const float mean = r1[0] * (1.f / 256.f);
    const float var = (r2[0] - 256.f * mean * mean) * (1.f / 255.f);
    const float sd = sqrtf(fmaxf(var, 0.f));
    const float o = a[t] * (v - mean) / (sd + 1e-6f) + bvec[t];
    out[(long)row * D_MODEL + t] = __float2bfloat16(o);
}

// ---------------------------------------------------------------------------
// Causal depthwise conv (k=4) + SiLU -> u (f32) + ub (bf16)
// ---------------------------------------------------------------------------
__global__ __launch_bounds__(256) void conv_silu_kernel(
    const float* __restrict__ xz, const float* __restrict__ cw,
    const float* __restrict__ cb, float* __restrict__ u, bf16* __restrict__ ub)
{
    const long i = (long)blockIdx.x * 256 + threadIdx.x;
    if (i >= (long)R_TOT * D_INNER) return;
    const int d = (int)(i % D_INNER);
    const long row = i / D_INNER;
    const int l = (int)(row % L_SEQ);
    const long b = row / L_SEQ;
    float s = cb[d];
#pragma unroll
    for (int k = 0; k < D_CONV; ++k) {
        const int ls = l - (D_CONV - 1) + k;
        if (ls >= 0)
            s += xz[((b * L_SEQ + ls) * (2 * D_INNER)) + d] * cw[d * D_CONV + k];
    }
    const float r = silu_f(s);
    u[i] = r;
    ub[i] = __float2bfloat16(r);
}

// ---------------------------------------------------------------------------
// Merged transpose: z<B -> dt, else u.  [B*L][1024] -> [B][1024][512]
// ---------------------------------------------------------------------------
__global__ __launch_bounds__(256) void trans2_kernel(
    const float* __restrict__ in0, float* __restrict__ out0,
    const float* __restrict__ in1, float* __restrict__ out1)
{
    __shared__ float t[64][65];
    const int db = blockIdx.x;
    const int lb = blockIdx.y;
    const int zz = blockIdx.z;
    const int which = (zz >= B_SZ) ? 1 : 0;
    const int b = zz - which * B_SZ;
    const float* in = which ? in1 : in0;
    float* out = which ? out1 : out0;
    const int tid = threadIdx.x;
    const int r  = tid >> 4;
    const int c4 = (tid & 15) * 4;

#pragma unroll
    for (int q = 0; q < 4; ++q) {
        const int lr = r + q * 16;
        const float4 v = *(const float4*)&in[((long)(b * L_SEQ + lb * 64 + lr)) * D_INNER + db * 64 + c4];
        t[lr][c4 + 0] = v.x; t[lr][c4 + 1] = v.y;
        t[lr][c4 + 2] = v.z; t[lr][c4 + 3] = v.w;
    }
    __syncthreads();
#pragma unroll
    for (int q = 0; q < 4; ++q) {
        const int dr = r + q * 16;
        float4 v;
        v.x = t[c4 + 0][dr]; v.y = t[c4 + 1][dr];
        v.z = t[c4 + 2][dr]; v.w = t[c4 + 3][dr];
        *(float4*)&out[((long)(b * D_INNER + db * 64 + dr)) * L_SEQ + lb * 64 + c4] = v;
    }
}

// ---------------------------------------------------------------------------
// Selective scan v4. One wave per (b,d). Per superstep of 8: compute yp[0..7]
// with NO cross-lane ops, then 8 independent interleaved shfl-reduction
// chains, then lane 0 stores 32 B contiguous to ysT[b][d][l].
// ---------------------------------------------------------------------------
__global__ __launch_bounds__(64) void scan_kernel(
    const float* __restrict__ dtT, const float* __restrict__ uT,
    const float* __restrict__ dbl, const float* __restrict__ A_log,
    float* __restrict__ ysT)
{
    const int blk = blockIdx.x;
    const int b = blk >> 10;
    const int d = blk & 1023;
    const int lane = threadIdx.x;
    const int n0 = lane * 2;

    const float An0 = -expf(A_log[(long)d * D_STATE + n0]);
    const float An1 = -expf(A_log[(long)d * D_STATE + n0 + 1]);
    float h0 = 0.f, h1 = 0.f;

    const float* dtp = dtT + ((long)(b * D_INNER + d) << 9);
    const float* up  = uT  + ((long)(b * D_INNER + d) << 9);
    const float* blp = dbl + (long)b * L_SEQ * DBL_LD + DT_RANK + n0;
    const float* clp = blp + D_STATE;
    float* ysp = ysT + ((long)(b * D_INNER + d) << 9);

    float4 dtc0 = *(const float4*)(dtp);
    float4 dtc1 = *(const float4*)(dtp + 4);
    float4 uc0  = *(const float4*)(up);
    float4 uc1  = *(const float4*)(up + 4);
    float2 Bc[8], Cc[8];
#pragma unroll
    for (int j = 0; j < 8; ++j) {
        Bc[j] = *(const float2*)(blp + (long)j * DBL_LD);
        Cc[j] = *(const float2*)(clp + (long)j * DBL_LD);
    }

    for (int s = 0; s < L_SEQ / 8; ++s) {
        const int nb = (s + 1) & (L_SEQ / 8 - 1);
        const float4 dtn0 = *(const float4*)(dtp + nb * 8);
        const float4 dtn1 = *(const float4*)(dtp + nb * 8 + 4);
        const float4 un0  = *(const float4*)(up + nb * 8);
        const float4 un1  = *(const float4*)(up + nb * 8 + 4);
        float2 Bn[8], Cn[8];
#pragma unroll
        for (int j = 0; j < 8; ++j) {
            Bn[j] = *(const float2*)(blp + (long)(nb * 8 + j) * DBL_LD);
            Cn[j] = *(const float2*)(clp + (long)(nb * 8 + j) * DBL_LD);
        }

        const float dts[8] = {dtc0.x, dtc0.y, dtc0.z, dtc0.w, dtc1.x, dtc1.y, dtc1.z, dtc1.w};
        const float us[8]  = {uc0.x,  uc0.y,  uc0.z,  uc0.w,  uc1.x,  uc1.y,  uc1.z,  uc1.w};
        float yp[8];
#pragma unroll
        for (int j = 0; j < 8; ++j) {
            const float dtv = dts[j];
            const float dtu = dtv * us[j];
            const float dA0 = expf(dtv * An0);
            const float dA1 = expf(dtv * An1);
            h0 = fmaf(dA0, h0, dtu * Bc[j].x);
            h1 = fmaf(dA1, h1, dtu * Bc[j].y);
            yp[j] = fmaf(h0, Cc[j].x, h1 * Cc[j].y);
        }
        // 8 independent reduction chains, interleaved (off-major order)
#pragma unroll
        for (int off = 32; off > 0; off >>= 1)
#pragma unroll
            for (int j = 0; j < 8; ++j)
                yp[j] += __shfl_down(yp[j], off);

        if (lane == 0) {
            float4 w0 = {yp[0], yp[1], yp[2], yp[3]};
            float4 w1 = {yp[4], yp[5], yp[6], yp[7]};
            *(float4*)(ysp + s * 8)     = w0;
            *(float4*)(ysp + s * 8 + 4) = w1;
        }

        dtc0 = dtn0; dtc1 = dtn1; uc0 = un0; uc1 = un1;
#pragma unroll
        for (int j = 0; j < 8; ++j) { Bc[j] = Bn[j]; Cc[j] = Cn[j]; }
    }
}

// ---------------------------------------------------------------------------
// Fused transpose + gate: y[row][d] = (ysT[b][d][l] + u*Dp) * silu(z) -> bf16
// grid (16, 8, B), 256 threads; LDS 64x64 tile for the ysT transpose.
// ---------------------------------------------------------------------------
__global__ __launch_bounds__(256) void gate_kernel(
    const float* __restrict__ ysT, const float* __restrict__ u,
    const float* __restrict__ Dp, const float* __restrict__ xz,
    bf16* __restrict__ y)
{
    __shared__ float t[64][65];
    const int db = blockIdx.x;
    const int lb = blockIdx.y;
    const int b  = blockIdx.z;
    const int tid = threadIdx.x;
    const int r  = tid >> 4;
    const int c4 = (tid & 15) * 4;

#pragma unroll
    for (int q = 0; q < 4; ++q) {
        const int dr = r + q * 16;
        const float4 v = *(const float4*)&ysT[(((long)(b * D_INNER + db * 64 + dr)) << 9) + lb * 64 + c4];
        t[dr][c4 + 0] = v.x; t[dr][c4 + 1] = v.y;
        t[dr][c4 + 2] = v.z; t[dr][c4 + 3] = v.w;
    }
    __syncthreads();

    const float4 dp4 = *(const float4*)&Dp[db * 64 + c4];
#pragma unroll
    for (int q = 0; q < 4; ++q) {
        const int lr = r + q * 16;
        const long row = (long)b * L_SEQ + lb * 64 + lr;
        const float4 u4 = *(const float4*)&u[row * D_INNER + db * 64 + c4];
        const float4 z4 = *(const float4*)&xz[row * 2 * D_INNER + D_INNER + db * 64 + c4];
        const float r0 = (t[c4 + 0][lr] + u4.x * dp4.x) * silu_f(z4.x);
        const float r1 = (t[c4 + 1][lr] + u4.y * dp4.y) * silu_f(z4.y);
        const float r2 = (t[c4 + 2][lr] + u4.z * dp4.z) * silu_f(z4.z);
        const float r3 = (t[c4 + 3][lr] + u4.w * dp4.w) * silu_f(z4.w);
        bf16 b0 = __float2bfloat16(r0), b1 = __float2bfloat16(r1);
        bf16 b2 = __float2bfloat16(r2), b3 = __float2bfloat16(r3);
        ushort4 pk;
        pk.x = *reinterpret_cast<unsigned short*>(&b0);
        pk.y = *reinterpret_cast<unsigned short*>(&b1);
        pk.z = *reinterpret_cast<unsigned short*>(&b2);
        pk.w = *reinterpret_cast<unsigned short*>(&b3);
        *reinterpret_cast<ushort4*>(y + row * D_INNER + db * 64 + c4) = pk;
    }
}

// ---------------------------------------------------------------------------
// Flash-style cross-attention -> bf16 (unchanged from round 6)
// ---------------------------------------------------------------------------
#define QT 64
#define CK 64

__global__ __launch_bounds__(256) void attn_kernel(
    const float* __restrict__ q, const float* __restrict__ k,
    const float* __restrict__ v, bf16* __restrict__ o)
{
    const int qt = blockIdx.x;
    const int hh = blockIdx.y;
    const int b  = blockIdx.z;
    const int t = threadIdx.x;
    const int lane = t & 7;
    const int qa = t >> 3;
    const int q0 = qt * QT + qa;
    const int q1 = q0 + 32;

    __shared__ float Ks[CK][36];
    __shared__ float Vs[CK][36];

    const float scale = 0.17677669529663687f;
    float qr0[32], qr1[32];
    {
        const float* q0p = q + ((long)(b * L_SEQ + q0) * D_MODEL + hh * DK);
        const float* q1p = q + ((long)(b * L_SEQ + q1) * D_MODEL + hh * DK);
#pragma unroll
        for (int i = 0; i < 8; ++i) {
            const float4 a = *(const float4*)&q0p[i * 4];
            const float4 c = *(const float4*)&q1p[i * 4];
            qr0[i*4+0] = a.x * scale; qr0[i*4+1] = a.y * scale;
            qr0[i*4+2] = a.z * scale; qr0[i*4+3] = a.w * scale;
            qr1[i*4+0] = c.x * scale; qr1[i*4+1] = c.y * scale;
            qr1[i*4+2] = c.z * scale; qr1[i*4+3] = c.w * scale;
        }
    }

    float m0 = -1e30f, l0 = 0.f, o0[32] = {};
    float m1 = -1e30f, l1 = 0.f, o1[32] = {};

    for (int c = 0; c < L_SEQ; c += CK) {
        __syncthreads();
        {
            const int fid = t * 2;
            const int row = fid >> 3;
            const int c0  = (fid & 7) * 4;
            const float* kp = k + ((long)(b * L_SEQ + c + row) * D_MODEL + hh * DK + c0);
            const float* vp = v + ((long)(b * L_SEQ + c + row) * D_MODEL + hh * DK + c0);
            *(float4*)&Ks[row][c0]     = *(const float4*)kp;
            *(float4*)&Ks[row][c0 + 4] = *(const float4*)(kp + 4);
            *(float4*)&Vs[row][c0]     = *(const float4*)vp;
            *(float4*)&Vs[row][c0 + 4] = *(const float4*)(vp + 4);
        }
        __syncthreads();

        float s0[8], s1[8];
#pragma unroll
        for (int i = 0; i < 8; ++i) {
            const int kk = i * 8 + lane;
            float a0 = 0.f, a1 = 0.f;
#pragma unroll
            for (int dd = 0; dd < 32; dd += 4) {
                const float4 kv = *(const float4*)&Ks[kk][dd];
                a0 = fmaf(qr0[dd+0], kv.x, a0); a0 = fmaf(qr0[dd+1], kv.y, a0);
                a0 = fmaf(qr0[dd+2], kv.z, a0); a0 = fmaf(qr0[dd+3], kv.w, a0);
                a1 = fmaf(qr1[dd+0], kv.x, a1); a1 = fmaf(qr1[dd+1], kv.y, a1);
                a1 = fmaf(qr1[dd+2], kv.z, a1); a1 = fmaf(qr1[dd+3], kv.w, a1);
            }
            s0[i] = a0; s1[i] = a1;
        }

        float cm0 = s0[0], cm1 = s1[0];
#pragma unroll
        for (int i = 1; i < 8; ++i) { cm0 = fmaxf(cm0, s0[i]); cm1 = fmaxf(cm1, s1[i]); }
#pragma unroll
        for (int off = 4; off > 0; off >>= 1) {
            cm0 = fmaxf(cm0, __shfl_down(cm0, off, 8));
            cm1 = fmaxf(cm1, __shfl_down(cm1, off, 8));
        }
        cm0 = __shfl(cm0, 0, 8);
        cm1 = __shfl(cm1, 0, 8);

        const float nm0 = fmaxf(m0, cm0);
        const float nm1 = fmaxf(m1, cm1);
        const float al0 = expf(m0 - nm0);
        const float al1 = expf(m1 - nm1);
        l0 *= al0; l1 *= al1;
#pragma unroll
        for (int dd = 0; dd < 32; ++dd) { o0[dd] *= al0; o1[dd] *= al1; }
        m0 = nm0; m1 = nm1;

        float p0[8], p1[8];
#pragma unroll
        for (int i = 0; i < 8; ++i) {
            p0[i] = expf(s0[i] - m0); l0 += p0[i];
            p1[i] = expf(s1[i] - m1); l1 += p1[i];
        }

#pragma unroll
        for (int i = 0; i < 8; ++i) {
            const int kk = i * 8 + lane;
#pragma unroll
            for (int dd = 0; dd < 32; dd += 4) {
                const float4 vv = *(const float4*)&Vs[kk][dd];
                o0[dd+0] = fmaf(p0[i], vv.x, o0[dd+0]);
                o0[dd+1] = fmaf(p0[i], vv.y, o0[dd+1]);
                o0[dd+2] = fmaf(p0[i], vv.z, o0[dd+2]);
                o0[dd+3] = fmaf(p0[i], vv.w, o0[dd+3]);
                o1[dd+0] = fmaf(p1[i], vv.x, o1[dd+0]);
                o1[dd+1] = fmaf(p1[i], vv.y, o1[dd+1]);
                o1[dd+2] = fmaf(p1[i], vv.z, o1[dd+2]);
                o1[dd+3] = fmaf(p1[i], vv.w, o1[dd+3]);
            }
        }
    }

#pragma unroll
    for (int off = 4; off > 0; off >>= 1) {
        l0 += __shfl_down(l0, off, 8);
        l1 += __shfl_down(l1, off, 8);
#pragma unroll
        for (int dd = 0; dd < 32; ++dd) {
            o0[dd] += __shfl_down(o0[dd], off, 8);
            o1[dd] += __shfl_down(o1[dd], off, 8);
        }
    }
    if (lane == 0) {
        const float i0 = 1.f / l0, i1 = 1.f / l1;
        bf16* op0 = o + ((long)(b * L_SEQ + q0) * D_MODEL + hh * DK);
        bf16* op1 = o + ((long)(b * L_SEQ + q1) * D_MODEL + hh * DK);
#pragma unroll
        for (int dd = 0; dd < 32; ++dd) {
            op0[dd] = __float2bfloat16(o0[dd] * i0);
            op1[dd] = __float2bfloat16(o1[dd] * i1);
        }
    }
}

// ---------------------------------------------------------------------------

extern "C" void kernel_launch(void* const* d_in, const int* in_sizes, int n_in,
                              void* d_out, int out_size, void* d_ws, size_t ws_size,
                              hipStream_t stream) {
    const float* X   = (const float*)d_in[0];
    const float* MEM = (const float*)d_in[1];
    const float* INW = (const float*)d_in[4];
    const float* CW  = (const float*)d_in[5];
    const float* CB  = (const float*)d_in[6];
    const float* XPW = (const float*)d_in[7];
    const float* DTW = (const float*)d_in[8];
    const float* DTB = (const float*)d_in[9];
    const float* ALG = (const float*)d_in[10];
    const float* DP  = (const float*)d_in[11];
    const float* OPW = (const float*)d_in[12];
    const float* N1A = (const float*)d_in[13];
    const float* N1B = (const float*)d_in[14];
    const float* N2A = (const float*)d_in[15];
    const float* N2B = (const float*)d_in[16];
    const float* N3A = (const float*)d_in[17];
    const float* N3B = (const float*)d_in[18];
    const float* WQ  = (const float*)d_in[19];
    const float* WQB = (const float*)d_in[20];
    const float* WKw = (const float*)d_in[21];
    const float* WKB = (const float*)d_in[22];
    const float* WVw = (const float*)d_in[23];
    const float* WVB = (const float*)d_in[24];
    const float* WO  = (const float*)d_in[25];
    const float* WOB = (const float*)d_in[26];
    const float* W1  = (const float*)d_in[27];
    const float* W1B = (const float*)d_in[28];
    const float* W2  = (const float*)d_in[29];
    const float* W2B = (const float*)d_in[30];
    float* out = (float*)d_out;

    // ---- bf16 arena ----
    bf16* bp = (bf16*)d_ws;
    bf16* ub   = bp;  bp += (long)R_TOT * D_INNER;
    bf16* ybb  = bp;  bp += (long)R_TOT * D_INNER;
    bf16* ffab = ybb;
    bf16* ln1b = bp;  bp += (long)R_TOT * D_MODEL;
    bf16* aob  = ln1b;
    bf16* ln2b = bp;  bp += (long)R_TOT * D_MODEL;
    bf16* ln3b = ln2b;
    bf16* arena = bp; bp += S_TOT;
    bf16* MEMb = arena;
    bf16* INWb = MEMb + S_MEM;
    bf16* XPWb = INWb + S_INW;
    bf16* OPWb = XPWb + S_XPW;
    bf16* WQb  = OPWb + S_OPW;
    bf16* WKb  = WQb + S_WQ;
    bf16* WVb  = WKb + S_WK;
    bf16* WOb  = WVb + S_WV;
    bf16* W1b  = WOb + S_WO;
    bf16* W2b  = W1b + S_W1;

    // ---- f32 buffers ----
    float* p = (float*)(bp + ((((long)(bp - (bf16*)d_ws)) & 1) ? 1 : 0));
    float* xz  = p;                                  p += (long)R_TOT * 2 * D_INNER;
    float* u   = p;                                  p += (long)R_TOT * D_INNER;
    float* uT  = p;                                  p += (long)R_TOT * D_INNER;
    float* dbl = p;                                  p += (long)R_TOT * DBL_LD;
    float* dtb = p;                                  p += (long)R_TOT * D_INNER;   // alias: ysT
    float* ysT = dtb;                                // scan out [b][d][l] (dtb dead)
    float* dtT = p;                                  p += (long)R_TOT * D_INNER;
    float* h1  = p;                                  p += (long)R_TOT * D_MODEL;
    float* qb  = p;                                  p += (long)R_TOT * D_MODEL;
    float* kb  = p;                                  p += (long)R_TOT * D_MODEL;
    float* vb  = p;                                  p += (long)R_TOT * D_MODEL;
    float* h2  = p;                                  p += (long)R_TOT * D_MODEL;

    const dim3 blk256(256);
    const long NE = (long)R_TOT * D_INNER;
    const int ew_grid = (int)((NE + 255) / 256);
    const int MT64 = R_TOT / 64;   // 16

    // 0. pack weights + memory to bf16
    pack_bf16<<<(S_TOT + 255) / 256, blk256, 0, stream>>>(
        MEM, INW, XPW, OPW, WQ, WKw, WVw, WO, W1, W2, arena);

    // 1. ln1 = LN(x) -> bf16
    ln_kernel<<<R_TOT, blk256, 0, stream>>>(X, N1A, N1B, ln1b);

    // 2. xz = ln1 @ in_proj^T   [R,2048] f32
    mfma_gemm<0><<<dim3(2 * D_INNER / 64, MT64), blk256, 0, stream>>>(
        ln1b, INWb, D_MODEL, xz, nullptr, 2 * D_INNER, nullptr, nullptr,
        R_TOT, 2 * D_INNER);

    // 3. u = silu(conv(xi)+cb) -> f32 + bf16
    conv_silu_kernel<<<ew_grid, blk256, 0, stream>>>(xz, CW, CB, u, ub);

    // 4. dbl = u @ x_proj^T   [R,272] f32
    mfma_gemm<0><<<dim3((DBL_LD + 63) / 64, MT64), blk256, 0, stream>>>(
        ub, XPWb, D_INNER, dbl, nullptr, DBL_LD, nullptr, nullptr,
        R_TOT, DBL_LD);

    // 5. dt = softplus(dbl[:,:16] @ dt_proj^T + b)  (f32 path, K=16)
    gemm_nt<2><<<dim3(D_INNER / GT, R_TOT / GT), blk256, 0, stream>>>(
        dbl, DBL_LD, DTW, DT_RANK, dtb, D_INNER, DTB, nullptr,
        R_TOT, D_INNER, DT_RANK);

    // 5b. merged transposes (dt, u) for scan
    trans2_kernel<<<dim3(D_INNER / 64, L_SEQ / 64, 2 * B_SZ), blk256, 0, stream>>>(
        dtb, dtT, u, uT);

    // 6. selective scan -> ysT [b][d][l] (aliases dtb)
    scan_kernel<<<B_SZ * D_INNER, dim3(64), 0, stream>>>(dtT, uT, dbl, ALG, ysT);

    // 7. gate (fused inverse transpose) -> bf16 y[row][d]
    gate_kernel<<<dim3(D_INNER / 64, L_SEQ / 64, B_SZ), blk256, 0, stream>>>(
        ysT, u, DP, xz, ybb);

    // 8. h1 = x + y @ out_proj^T  f32
    mfma_gemm<0><<<dim3(D_MODEL / 64, MT64), blk256, 0, stream>>>(
        ybb, OPWb, D_INNER, h1, nullptr, D_MODEL, nullptr, X,
        R_TOT, D_MODEL);

    // 9. ln2 -> bf16
    ln_kernel<<<R_TOT, blk256, 0, stream>>>(h1, N2A, N2B, ln2b);

    // 10-12. q,k,v
    mfma_gemm<0><<<dim3(D_MODEL / 64, MT64), blk256, 0, stream>>>(
        ln2b, WQb, D_MODEL, qb, nullptr, D_MODEL, WQB, nullptr, R_TOT, D_MODEL);
    mfma_gemm<0><<<dim3(D_MODEL / 64, MT64), blk256, 0, stream>>>(
        MEMb, WKb, D_MODEL, kb, nullptr, D_MODEL, WKB, nullptr, R_TOT, D_MODEL);
    mfma_gemm<0><<<dim3(D_MODEL / 64, MT64), blk256, 0, stream>>>(
        MEMb, WVb, D_MODEL, vb, nullptr, D_MODEL, WVB, nullptr, R_TOT, D_MODEL);

    // 13. attention -> bf16
    attn_kernel<<<dim3(L_SEQ / QT, N_HEADS, B_SZ), blk256, 0, stream>>>(qb, kb, vb, aob);

    // 14. h2 = h1 + ao @ wo^T + wo_b  f32
    mfma_gemm<0><<<dim3(D_MODEL / 64, MT64), blk256, 0, stream>>>(
        aob, WOb, D_MODEL, h2, nullptr, D_MODEL, WOB, h1, R_TOT, D_MODEL);

    // 15. ln3 -> bf16
    ln_kernel<<<R_TOT, blk256, 0, stream>>>(h2, N3A, N3B, ln3b);

    // 16. ffa = relu(ln3 @ w1^T + b) -> bf16
    mfma_gemm<1><<<dim3(D_FF / 64, MT64), blk256, 0, stream>>>(
        ln3b, W1b, D_MODEL, nullptr, ffab, D_FF, W1B, nullptr, R_TOT, D_FF);

    // 17. out = h2 + ffa @ w2^T + b  f32
    mfma_gemm<0><<<dim3(D_MODEL / 64, MT64), blk256, 0, stream>>>(
        ffab, W2b, D_FF, out, nullptr, D_MODEL, W2B, h2, R_TOT, D_MODEL);

    (void)in_sizes; (void)n_in; (void)out_size; (void)ws_size;
}